// Round 1
// baseline (2995.215 us; speedup 1.0000x reference)
//
#include <hip/hip_runtime.h>

// B=32, S=128, D=300 (pad 320), VOCAB=20000 (625 chunks of 32), K=8.
// Inputs may be f32 or bf16 (runtime-detected); canonicalized to bf16 in ws.

typedef unsigned short u16;
typedef unsigned int   u32;
typedef float  f32x4 __attribute__((ext_vector_type(4)));
typedef u32    u32x4 __attribute__((ext_vector_type(4)));
typedef __bf16 bf16x8 __attribute__((ext_vector_type(8)));
typedef _Float16 f16x2 __attribute__((ext_vector_type(2)));
typedef _Float16 f16x8 __attribute__((ext_vector_type(8)));

__device__ __forceinline__ float bf2f(u16 u) { return __uint_as_float(((u32)u) << 16); }
__device__ __forceinline__ u16 f2bf(float f) {
  u32 x = __float_as_uint(f);
  u32 r = (x + 0x7fffu + ((x >> 16) & 1u)) >> 16;  // RNE
  return (u16)r;
}
__device__ __forceinline__ u16 f2h(float f) {
  union { _Float16 h; u16 u; } cv; cv.h = (_Float16)f; return cv.u;
}
__device__ __forceinline__ float h2f(u16 u) {
  union { _Float16 h; u16 u; } cv; cv.u = u; return (float)cv.h;
}
__device__ __forceinline__ float sigm_fast(float x) {
  return __builtin_amdgcn_rcpf(1.f + __expf(-x));
}
__device__ __forceinline__ float tanh_fast(float x) {
  return 1.f - 2.f * __builtin_amdgcn_rcpf(1.f + __expf(2.f * x));
}

// quad_perm DPP move (4-lane group permutation, VALU-only cross-lane)
template <int CTRL>
__device__ __forceinline__ float dppq(float v) {
  return __uint_as_float(
      (u32)__builtin_amdgcn_mov_dpp((int)__float_as_uint(v), CTRL, 0xF, 0xF, true));
}

__device__ __forceinline__ f32x4 shflx4(f32x4 v, int m) {
  f32x4 r;
  r[0] = __shfl_xor(v[0], m, 16);
  r[1] = __shfl_xor(v[1], m, 16);
  r[2] = __shfl_xor(v[2], m, 16);
  r[3] = __shfl_xor(v[3], m, 16);
  return r;
}

// ---------- ingest: detect f32 vs bf16, canonicalize all float inputs to bf16 ----------
__device__ __forceinline__ void conv_seg(const void* src, u16* dst, int n, int is32,
                                         int t0, int stride) {
  if (is32) {
    const float* s = (const float*)src;
    for (int i = t0; i < n; i += stride) dst[i] = f2bf(s[i]);
  } else {
    const u16* s = (const u16*)src;
    for (int i = t0; i < n; i += stride) dst[i] = s[i];
  }
}

__global__ __launch_bounds__(256) void k_ingest(
    const void* words, const void* vocab, const void* de, const void* W,
    const void* lWih, const void* lWhh, const void* lbih, const void* lbhh,
    const void* rWih, const void* rWhh, const void* rbih, const void* rbhh,
    u16* cw, u16* cv, u16* cde, u16* cW, u16* cWih, u16* cWhh, u16* cbih, u16* cbhh,
    u16* crWih, u16* crWhh, u16* crbih, u16* crbhh, u32* flag) {
  __shared__ int s_is32;
  int tid = threadIdx.x;
  int vote = 0;
  if (tid < 64) {
    u32 w = ((const u32*)words)[tid];
    int e = (w >> 7) & 0xFF;  // bf16 low-element exponent field if bf16-packed
    vote = (e >= 100 && e <= 150) ? 1 : 0;
  }
  unsigned long long m = __ballot(vote);
  if (tid == 0) s_is32 = (__popcll(m) < 32) ? 1 : 0;  // few plausible bf16 exps -> f32
  __syncthreads();
  int is32 = s_is32;
  if (blockIdx.x == 0 && tid == 0) *flag = (u32)is32;
  int t0 = blockIdx.x * 256 + tid;
  int stride = gridDim.x * 256;
  conv_seg(words, cw, 1228800, is32, t0, stride);
  conv_seg(vocab, cv, 6000000, is32, t0, stride);
  conv_seg(de, cde, 300, is32, t0, stride);
  conv_seg(W, cW, 90000, is32, t0, stride);
  conv_seg(lWih, cWih, 360000, is32, t0, stride);
  conv_seg(lWhh, cWhh, 360000, is32, t0, stride);
  conv_seg(lbih, cbih, 1200, is32, t0, stride);
  conv_seg(lbhh, cbhh, 1200, is32, t0, stride);
  conv_seg(rWih, crWih, 90000, is32, t0, stride);
  conv_seg(rWhh, crWhh, 90000, is32, t0, stride);
  conv_seg(rbih, crbih, 300, is32, t0, stride);
  conv_seg(rbhh, crbhh, 300, is32, t0, stride);
}

// ---------- transpose bf16 (J x K) -> bf16 (K x J) ----------
__global__ __launch_bounds__(256) void k_transpose_bf(const u16* __restrict__ in,
                                                      u16* __restrict__ out,
                                                      int J, int K) {
  __shared__ u16 t[32][33];
  int j0 = blockIdx.x * 32, k0 = blockIdx.y * 32;
  int lx = threadIdx.x & 31, ly = threadIdx.x >> 5;
  for (int r = ly; r < 32; r += 8) {
    int j = j0 + r, k = k0 + lx;
    t[r][lx] = (j < J && k < K) ? in[(size_t)j * K + k] : (u16)0;
  }
  __syncthreads();
  for (int r = ly; r < 32; r += 8) {
    int k = k0 + r, j = j0 + lx;
    if (k < K && j < J) out[(size_t)k * J + j] = t[lx][r];
  }
}

// ---------- pack lstm_Whh -> per-wave MFMA B-frag slices (f16), gate-interleaved ----------
// Global col n = w*80 + j*16 + n16; local = j*16+n16; dd = local>>2; gate = n16&3;
// dim = w*20+dd; k = kt*32+(lane>>4)*8+jj; val = Whh[gate*300+dim][k] (0 pad).
// Layout: pW[(((w*5 + j)*10 + kt)*64 + lane)*8 + jj] f16, total 409600.
__global__ __launch_bounds__(256) void k_pack_w5(const u16* __restrict__ Whh,
                                                 u16* __restrict__ pW) {
  int idx = blockIdx.x * 256 + threadIdx.x;
  if (idx >= 409600) return;
  int jj = idx & 7;
  int lane = (idx >> 3) & 63;
  int rest = idx >> 9;       // 0..799 = (w*5+j)*10 + kt
  int kt = rest % 10;
  int t2 = rest / 10;        // 0..79 = w*5 + j
  int j = t2 % 5;
  int w = t2 / 5;
  int n16 = lane & 15;
  int g2 = n16 & 3;
  int local = j * 16 + n16;
  int dd = local >> 2;
  int dim = w * 20 + dd;
  int k = kt * 32 + ((lane >> 4) * 8) + jj;
  u16 out = 0;
  if (dim < 300 && k < 300)
    out = f2h(bf2f(Whh[(size_t)(g2 * 300 + dim) * 300 + k]));
  pW[idx] = out;
}

// ---------- pack vocab into MFMA operand layouts ----------
__global__ __launch_bounds__(256) void k_pack_vocab(const u16* __restrict__ vocab,
                                                    u16* __restrict__ pA,
                                                    u16* __restrict__ pB) {
  __shared__ u16 sv[32][320];
  int ci = blockIdx.x, tid = threadIdx.x;
  for (int idx = tid; idx < 32 * 20; idx += 256) {
    int v = idx / 20, k = 300 + (idx - v * 20);
    sv[v][k] = 0;
  }
  for (int idx = tid; idx < 32 * 300; idx += 256) {
    int v = idx / 300, k = idx - v * 300;
    sv[v][k] = vocab[(size_t)(ci * 32 + v) * 300 + k];
  }
  __syncthreads();
  for (int idx = tid; idx < 10240; idx += 256) {
    int j = idx & 7, lane = (idx >> 3) & 63, t2 = idx >> 9;
    int kk = t2 % 10, h = t2 / 10;
    int v = h * 16 + (lane & 15);
    int k = kk * 32 + ((lane >> 4)) * 8 + j;
    pA[(size_t)ci * 10240 + (size_t)idx] = sv[v][k];
  }
  for (int idx = tid; idx < 9728; idx += 256) {
    int j = idx & 7, lane = (idx >> 3) & 63, nc = idx >> 9;
    int v = (lane >> 4) * 8 + j;
    int n = nc * 16 + (lane & 15);
    pB[(size_t)ci * 9728 + (size_t)idx] = sv[v][n];
  }
}

// ---------- X = words @ W -> bf16 (4096 x 320, zero pad) ----------
__global__ __launch_bounds__(256) void k_xw(const u16* __restrict__ words,
                                            const u16* __restrict__ W,
                                            u16* __restrict__ X) {
  __shared__ float As[300][33];
  int n0 = blockIdx.x * 128;
  int r0 = blockIdx.y * 32;
  int tid = threadIdx.x;
  for (int idx = tid; idx < 32 * 300; idx += 256) {
    int r = idx / 300, k = idx - r * 300;
    As[k][r] = bf2f(words[(size_t)(r0 + r) * 300 + k]);
  }
  __syncthreads();
  int j = n0 + (tid & 127);
  int rh = (tid >> 7) * 16;
  float acc[16];
#pragma unroll
  for (int i = 0; i < 16; i++) acc[i] = 0.f;
  if (j < 300) {
    for (int k = 0; k < 300; k++) {
      float bw = bf2f(W[(size_t)k * 300 + j]);
#pragma unroll
      for (int i = 0; i < 16; i++) acc[i] += As[k][rh + i] * bw;
    }
  }
  if (j < 320) {
#pragma unroll
    for (int i = 0; i < 16; i++) {
      float v = (j < 300) ? acc[i] : 0.f;
      X[(size_t)(r0 + rh + i) * 320 + j] = f2bf(v);
    }
  }
}

// ---------- flash-style softmax-weighted vocab sum (MFMA), per-slice partials ----------
__global__ __launch_bounds__(512, 2) void k_softmax_v(
    const u16* __restrict__ X, const u16* __restrict__ pA, const u16* __restrict__ pB,
    u16* __restrict__ pAcc, float* __restrict__ pML) {
  __shared__ __align__(16) u16 chunk[19968];
  __shared__ __align__(16) float ptbuf[8 * 576];
  int bid = blockIdx.x;
  int sl = bid & 7, b = bid >> 3;
  int tid = threadIdx.x;
  int w = tid >> 6, lane = tid & 63;
  int quad = lane >> 4, n16 = lane & 15;
  int cs = (sl == 0) ? 0 : 79 + (sl - 1) * 78;
  int nch = (sl == 0) ? 79 : 78;

  int rowA = b * 128 + w * 16 + n16;
  const bf16x8* Xrow = (const bf16x8*)(X + (size_t)rowA * 320);
  bf16x8 afr[10];
#pragma unroll
  for (int kk = 0; kk < 10; kk++) afr[kk] = Xrow[kk * 4 + quad];

  f32x4 acc[19];
#pragma unroll
  for (int i = 0; i < 19; i++) { acc[i][0] = 0.f; acc[i][1] = 0.f; acc[i][2] = 0.f; acc[i][3] = 0.f; }
  f32x4 mrun, lrun;
#pragma unroll
  for (int c = 0; c < 4; c++) { mrun[c] = -1e30f; lrun[c] = 0.f; }
  float* myPt = ptbuf + w * 576;

  {
    const u32x4* gA = (const u32x4*)pA + (size_t)cs * 1280;
    const u32x4* gB = (const u32x4*)pB + (size_t)cs * 1216;
    u32x4* sb = (u32x4*)&chunk[0];
    for (int idx = tid; idx < 2496; idx += 512)
      sb[idx] = (idx < 1280) ? gA[idx] : gB[idx - 1280];
  }
  __syncthreads();

  for (int ic = 0; ic < nch; ic++) {
    u32x4 pf[5];
    bool havepf = (ic + 1 < nch);
    if (havepf) {
      int ci = cs + ic + 1;
      const u32x4* gA = (const u32x4*)pA + (size_t)ci * 1280;
      const u32x4* gB = (const u32x4*)pB + (size_t)ci * 1216;
#pragma unroll
      for (int i = 0; i < 5; i++) {
        int idx = tid + i * 512;
        if (idx < 2496) pf[i] = (idx < 1280) ? gA[idx] : gB[idx - 1280];
      }
    }
    const bf16x8* bufA = (const bf16x8*)&chunk[0];
    const bf16x8* bufB = (const bf16x8*)&chunk[10240];
    f32x4 L0, L1;
#pragma unroll
    for (int c = 0; c < 4; c++) { L0[c] = 0.f; L1[c] = 0.f; }
#pragma unroll
    for (int kk = 0; kk < 10; kk++) {
      L0 = __builtin_amdgcn_mfma_f32_16x16x32_bf16(afr[kk], bufA[kk * 64 + lane], L0, 0, 0, 0);
      L1 = __builtin_amdgcn_mfma_f32_16x16x32_bf16(afr[kk], bufA[(10 + kk) * 64 + lane], L1, 0, 0, 0);
    }
    f32x4 t;
#pragma unroll
    for (int c = 0; c < 4; c++) t[c] = fmaxf(L0[c], L1[c]);
#pragma unroll
    for (int off = 1; off < 16; off <<= 1) {
      f32x4 o = shflx4(t, off);
#pragma unroll
      for (int c = 0; c < 4; c++) t[c] = fmaxf(t[c], o[c]);
    }
    f32x4 mnew, al, P0v, P1v, rs;
#pragma unroll
    for (int c = 0; c < 4; c++) {
      mnew[c] = fmaxf(mrun[c], t[c]);
      al[c] = __expf(mrun[c] - mnew[c]);
      P0v[c] = __expf(L0[c] - mnew[c]);
      P1v[c] = __expf(L1[c] - mnew[c]);
      rs[c] = P0v[c] + P1v[c];
    }
#pragma unroll
    for (int off = 1; off < 16; off <<= 1) {
      f32x4 o = shflx4(rs, off);
#pragma unroll
      for (int c = 0; c < 4; c++) rs[c] += o[c];
    }
#pragma unroll
    for (int c = 0; c < 4; c++) { lrun[c] = lrun[c] * al[c] + rs[c]; mrun[c] = mnew[c]; }
#pragma unroll
    for (int r = 0; r < 4; r++) {
      myPt[(quad * 4 + r) * 36 + n16] = P0v[r];
      myPt[(quad * 4 + r) * 36 + 16 + n16] = P1v[r];
    }
    __syncthreads();
    f32x4 plo = *(const f32x4*)(myPt + n16 * 36 + quad * 8);
    f32x4 phi = *(const f32x4*)(myPt + n16 * 36 + quad * 8 + 4);
    bf16x8 paf;
#pragma unroll
    for (int c = 0; c < 4; c++) { paf[c] = (__bf16)plo[c]; paf[c + 4] = (__bf16)phi[c]; }
#pragma unroll
    for (int nc = 0; nc < 19; nc++) {
      f32x4 a = acc[nc];
#pragma unroll
      for (int c = 0; c < 4; c++) a[c] *= al[c];
      acc[nc] = __builtin_amdgcn_mfma_f32_16x16x32_bf16(paf, bufB[nc * 64 + lane], a, 0, 0, 0);
    }
    __syncthreads();
    if (havepf) {
      u32x4* sb = (u32x4*)&chunk[0];
#pragma unroll
      for (int i = 0; i < 5; i++) {
        int idx = tid + i * 512;
        if (idx < 2496) sb[idx] = pf[i];
      }
    }
    __syncthreads();
  }

  size_t prow = (size_t)sl * 4096 + (size_t)b * 128 + w * 16;
  if (n16 == 0) {
#pragma unroll
    for (int r = 0; r < 4; r++) {
      pML[(prow + quad * 4 + r) * 2 + 0] = mrun[r];
      pML[(prow + quad * 4 + r) * 2 + 1] = lrun[r];
    }
  }
#pragma unroll
  for (int nc = 0; nc < 19; nc++)
#pragma unroll
    for (int r = 0; r < 4; r++)
      pAcc[(prow + quad * 4 + r) * 304 + nc * 16 + n16] = f2bf(acc[nc][r]);
}

// ---------- combine slices + default-embed column -> V bf16 (4096 x 320) ----------
__global__ __launch_bounds__(320) void k_combine(
    const u16* __restrict__ pAcc, const float* __restrict__ pML,
    const u16* __restrict__ X, const u16* __restrict__ de,
    const u16* __restrict__ words, u16* __restrict__ Vout) {
  __shared__ float red[320];
  __shared__ float fs[8];
  __shared__ float sinv, sw;
  int row = blockIdx.x, tid = threadIdx.x;
  float p = 0.f;
  if (tid < 300) p = bf2f(X[(size_t)row * 320 + tid]) * bf2f(de[tid]);
  red[tid] = p;
  __syncthreads();
  if (tid == 0) {
    float d = 0.f;
    for (int i = 0; i < 300; i++) d += red[i];
    float mv[8], lv[8], ms = -1e30f;
    for (int s = 0; s < 8; s++) {
      mv[s] = pML[((size_t)s * 4096 + row) * 2];
      lv[s] = pML[((size_t)s * 4096 + row) * 2 + 1];
      ms = fmaxf(ms, mv[s]);
    }
    float mf = fmaxf(ms, d);
    float pd = __expf(d - mf);
    float l = pd;
    for (int s = 0; s < 8; s++) {
      float f = __expf(mv[s] - mf);
      fs[s] = f;
      l += lv[s] * f;
    }
    sinv = 1.f / l;
    sw = pd / l;
  }
  __syncthreads();
  float v = 0.f;
  if (tid < 300) {
    float a = 0.f;
#pragma unroll
    for (int s = 0; s < 8; s++)
      a += bf2f(pAcc[((size_t)s * 4096 + row) * 304 + tid]) * fs[s];
    v = a * sinv + sw * bf2f(words[(size_t)row * 300 + tid]);
  }
  Vout[(size_t)row * 320 + tid] = f2bf(v);
}

// ---------- xg = V @ lstm_Wih.T + bih + bhh (f32, 4096 x 1200, row-major) ----------
__global__ __launch_bounds__(256) void k_xg(const u16* __restrict__ Vb,
                                            const u16* __restrict__ WihT,
                                            const u16* __restrict__ bih,
                                            const u16* __restrict__ bhh,
                                            float* __restrict__ xg) {
  __shared__ float As[300][33];
  int n0 = blockIdx.x * 128;
  int r0 = blockIdx.y * 32;
  int tid = threadIdx.x;
  for (int idx = tid; idx < 32 * 300; idx += 256) {
    int r = idx / 300, k = idx - r * 300;
    As[k][r] = bf2f(Vb[(size_t)(r0 + r) * 320 + k]);
  }
  __syncthreads();
  int j = n0 + (tid & 127);
  if (j >= 1200) return;
  int rh = (tid >> 7) * 16;
  float acc[16];
#pragma unroll
  for (int i = 0; i < 16; i++) acc[i] = 0.f;
  for (int k = 0; k < 300; k++) {
    float bw = bf2f(WihT[(size_t)k * 1200 + j]);
#pragma unroll
    for (int i = 0; i < 16; i++) acc[i] += As[k][rh + i] * bw;
  }
  float bias = bf2f(bih[j]) + bf2f(bhh[j]);
#pragma unroll
  for (int i = 0; i < 16; i++)
    xg[(size_t)(r0 + rh + i) * 1200 + j] = acc[i] + bias;
}

// ---------- repack xg: [b*128+t][gate*300+dim] f32 -> xgp[((t*2+bm)*1280 + n)*16 + bl]
// n = w*80 + dd*4 + gate (gate-interleaved cols, batch-inner-16 for MFMA C-init loads)
__global__ __launch_bounds__(256) void k_repack_xg(const float* __restrict__ xg,
                                                   float* __restrict__ xgp) {
  __shared__ float s[16][81];
  int bid = blockIdx.x;
  int t = bid & 127, bm = bid >> 7;
  int tid = threadIdx.x;
  for (int w = 0; w < 16; w++) {
    for (int e = tid; e < 1280; e += 256) {
      int bl = e / 80, local = e - bl * 80;
      int g2 = local / 20, dd = local - g2 * 20;
      int dim = w * 20 + dd;
      float v = 0.f;
      if (dim < 300)
        v = xg[((size_t)(bm * 16 + bl) * 128 + t) * 1200 + g2 * 300 + dim];
      s[bl][dd * 4 + g2] = v;
    }
    __syncthreads();
    size_t ob = ((size_t)(t * 2 + bm) * 1280 + w * 80) * 16;
    for (int e = tid; e < 1280; e += 256) {
      int nl = e >> 4, bl = e & 15;
      xgp[ob + e] = s[bl][nl];
    }
    __syncthreads();
  }
}

// ---------- LSTM: 2 independent blocks x 16 batches, single-CU, LDS h-exchange ----------
// Batches are recurrence-independent -> no inter-block sync. 16 waves; wave w owns
// 5 col-tiles (cols w*80..w*80+79 = dims w*20..w*20+19 x 4 gates interleaved).
// Weights register-resident (200 VGPR/wave). Per step: ds_read h A-frags from
// double-buffered LDS -> 50 MFMA (C init = xg) -> DPP 4x4 transpose (i,f,g,o in-lane)
// -> activations in regs -> f16 h store to other LDS buffer -> one __syncthreads.
__global__ __launch_bounds__(1024, 1) void k_lstm3(
    const float* __restrict__ xgp, const u16* __restrict__ pW,
    const int* __restrict__ lengths, float* __restrict__ qbuf) {
  __shared__ u16 hs[2][16][328];  // stride 328 f16 = 164 dwords -> conflict-free b128 reads
  __shared__ int s_maxlen;
  int bm = blockIdx.x, tid = threadIdx.x;
  int w = tid >> 6, lane = tid & 63;
  int quad = lane >> 4, n16 = lane & 15;
  int g = n16 & 3, q4 = n16 >> 2;
  for (int i = tid; i < 2 * 16 * 328; i += 1024) ((u16*)hs)[i] = 0;
  {
    int lv = (lane < 16) ? lengths[bm * 16 + lane] : 0;
#pragma unroll
    for (int off = 1; off < 16; off <<= 1) {
      int o = __shfl_xor(lv, off, 64);
      lv = lv > o ? lv : o;
    }
    if (tid == 0) s_maxlen = lv;
  }
  // weights: B-frags, constant across steps
  f16x8 bf[5][10];
  const u32x4* pw4 = (const u32x4*)pW;
#pragma unroll
  for (int j = 0; j < 5; j++)
#pragma unroll
    for (int kt = 0; kt < 10; kt++)
      bf[j][kt] = __builtin_bit_cast(f16x8, pw4[((w * 5 + j) * 10 + kt) * 64 + lane]);
  int b = quad * 4 + g;                  // batch (local) this lane owns post-transpose
  int len_b = lengths[bm * 16 + b];
  float c[5], h[5];
#pragma unroll
  for (int j = 0; j < 5; j++) { c[j] = 0.f; h[j] = 0.f; }
  // xg C-init loads: xgp[((t*2+bm)*1280 + w*80 + j*16 + n16)*16 + quad*4 ..+3]
  const f32x4* xp0 = (const f32x4*)xgp + ((size_t)bm * 1280 + w * 80 + n16) * 4 + quad;
  f32x4 xv[5];
#pragma unroll
  for (int j = 0; j < 5; j++) xv[j] = xp0[j * 64];
  __syncthreads();
  int maxlen = s_maxlen;
  for (int t = 0; t < maxlen; t++) {
    f32x4 acc[5];
#pragma unroll
    for (int j = 0; j < 5; j++) acc[j] = xv[j];
    if (t + 1 < maxlen) {  // prefetch next step's xg; lands during compute phase
      const f32x4* xp = xp0 + (size_t)(t + 1) * 10240;
#pragma unroll
      for (int j = 0; j < 5; j++) xv[j] = xp[j * 64];
    }
    // A-frags: h_{t} for 16 batches (f16), from buffer t&1
    const u16* hr = &hs[t & 1][0][0];
    u32x4 af[10];
#pragma unroll
    for (int kt = 0; kt < 10; kt++)
      af[kt] = *(const u32x4*)(hr + n16 * 328 + kt * 32 + quad * 8);
#pragma unroll
    for (int kt = 0; kt < 10; kt++) {
      f16x8 a = __builtin_bit_cast(f16x8, af[kt]);
#pragma unroll
      for (int j = 0; j < 5; j++)
        acc[j] = __builtin_amdgcn_mfma_f32_16x16x32_f16(a, bf[j][kt], acc[j], 0, 0, 0);
    }
    u16* hw = (u16*)&hs[(t + 1) & 1][0][0];
    bool upd = (t < len_b);
#pragma unroll
    for (int j = 0; j < 5; j++) {
      // lanes 4k..4k+3 hold gates 0..3 (cols dd*4+g) for rows quad*4+0..3.
      // DPP quad_perm 4x4 transpose -> lane g holds all 4 gates of row quad*4+g.
      float v0 = acc[j][0], v1 = acc[j][1], v2 = acc[j][2], v3 = acc[j][3];
      float x0 = dppq<0xB1>(v0), x1 = dppq<0xB1>(v1);
      float x2 = dppq<0xB1>(v2), x3 = dppq<0xB1>(v3);
      bool o1 = (g & 1);
      float m0 = o1 ? x1 : v0;
      float m1 = o1 ? v1 : x0;
      float m2 = o1 ? x3 : v2;
      float m3 = o1 ? v3 : x2;
      float y0 = dppq<0x4E>(m0), y1 = dppq<0x4E>(m1);
      float y2 = dppq<0x4E>(m2), y3 = dppq<0x4E>(m3);
      bool o2 = (g & 2);
      float F0 = o2 ? y2 : m0;  // i
      float F1 = o2 ? y3 : m1;  // f
      float F2 = o2 ? m2 : y0;  // g
      float F3 = o2 ? m3 : y1;  // o
      float ii = sigm_fast(F0), ff = sigm_fast(F1);
      float gg = tanh_fast(F2), oo = sigm_fast(F3);
      float cn = ff * c[j] + ii * gg;
      float hn = oo * tanh_fast(cn);
      c[j] = upd ? cn : c[j];
      h[j] = upd ? hn : h[j];
      int dim = w * 20 + j * 4 + q4;
      if (dim < 300) hw[b * 328 + dim] = f2h(h[j]);
    }
    __syncthreads();
  }
  // final q = h (frozen at len per batch)
#pragma unroll
  for (int j = 0; j < 5; j++) {
    int dim = w * 20 + j * 4 + q4;
    if (dim < 300) qbuf[(size_t)(bm * 16 + b) * 304 + dim] = h[j];
  }
}

// ---------- RNN tail: q from qbuf (f32), 8 steps h2 = tanh(base + h2@rWhh.T) ----------
__global__ __launch_bounds__(320) void k_rnn(
    const float* __restrict__ qbuf,
    const u16* __restrict__ rWihT, const u16* __restrict__ rWhhT,
    const u16* __restrict__ rbih, const u16* __restrict__ rbhh,
    float* __restrict__ H) {
  __shared__ float qs[304], h2[304], base[304];
  int b = blockIdx.x, tid = threadIdx.x;
  if (tid < 304) {
    qs[tid] = (tid < 300) ? qbuf[(size_t)b * 304 + tid] : 0.f;
    h2[tid] = 0.f;
  }
  __syncthreads();
  if (tid < 300) {
    float a = bf2f(rbih[tid]) + bf2f(rbhh[tid]);
    for (int k = 0; k < 300; k++) a += qs[k] * bf2f(rWihT[(size_t)k * 300 + tid]);
    base[tid] = a;
  }
  __syncthreads();
  for (int s = 0; s < 8; s++) {
    float nv = 0.f;
    if (tid < 300) {
      float a = base[tid];
      for (int k = 0; k < 300; k++) a += h2[k] * bf2f(rWhhT[(size_t)k * 300 + tid]);
      nv = tanhf(a);
    }
    __syncthreads();
    if (tid < 300) {
      h2[tid] = nv;
      H[((size_t)b * 8 + s) * 300 + tid] = nv;
    }
    __syncthreads();
  }
}

// ---------- attention readout ----------
__global__ __launch_bounds__(256) void k_attn(const float* __restrict__ H,
                                              const u16* __restrict__ Vb,
                                              const int* __restrict__ lengths,
                                              const u32* __restrict__ flag,
                                              void* __restrict__ dout) {
  __shared__ float Hs[8][304];
  __shared__ float sc[8][128];
  __shared__ float wsum[8];
  int b = blockIdx.x, tid = threadIdx.x;
  int len = lengths[b];
  int is32 = (int)*flag;
  for (int idx = tid; idx < 8 * 300; idx += 256) {
    int k = idx / 300, j = idx - k * 300;
    Hs[k][j] = H[((size_t)b * 8 + k) * 300 + j];
  }
  __syncthreads();
  for (int s = tid; s < len; s += 256) {
    const u16* vr = Vb + (size_t)(b * 128 + s) * 320;
    float a[8];
#pragma unroll
    for (int k = 0; k < 8; k++) a[k] = 0.f;
    for (int j = 0; j < 300; j++) {
      float v = bf2f(vr[j]);
#pragma unroll
      for (int k = 0; k < 8; k++) a[k] += Hs[k][j] * v;
    }
#pragma unroll
    for (int k = 0; k < 8; k++) sc[k][s] = a[k];
  }
  __syncthreads();
  if (tid < 8) {
    float m = -1e30f;
    for (int s = 0; s < len; s++) m = fmaxf(m, sc[tid][s]);
    float l = 0.f;
    for (int s = 0; s < len; s++) { float e = __expf(sc[tid][s] - m); sc[tid][s] = e; l += e; }
    wsum[tid] = 1.f / l;
  }
  __syncthreads();
  int k = tid >> 5, jl = tid & 31;
  for (int j = jl; j < 300; j += 32) {
    float a = 0.f;
    for (int s = 0; s < len; s++) a += sc[k][s] * bf2f(Vb[(size_t)(b * 128 + s) * 320 + j]);
    float val = a * wsum[k];
    size_t o = ((size_t)b * 8 + k) * 300 + j;
    if (is32) ((float*)dout)[o] = val;
    else ((u16*)dout)[o] = f2bf(val);
  }
}

extern "C" void kernel_launch(void* const* d_in, const int* in_sizes, int n_in,
                              void* d_out, int out_size, void* d_ws, size_t ws_size,
                              hipStream_t stream) {
  (void)in_sizes; (void)n_in; (void)out_size; (void)ws_size;
  const void* words = d_in[0];
  const int* lengths = (const int*)d_in[1];
  const void* vocab = d_in[2];
  const void* de = d_in[3];
  const void* W = d_in[4];
  const void* lWih = d_in[5];
  const void* lWhh = d_in[6];
  const void* lbih = d_in[7];
  const void* lbhh = d_in[8];
  const void* rWih = d_in[9];
  const void* rWhh = d_in[10];
  const void* rbih = d_in[11];
  const void* rbhh = d_in[12];

  char* basep = (char*)d_ws;
  size_t off = 0;
  auto take = [&](size_t bytes) -> char* {
    char* p = basep + off;
    off += (bytes + 255) & ~(size_t)255;
    return p;
  };
  u16* cw    = (u16*)take(1228800 * 2);
  u16* cv    = (u16*)take(6000000 * 2);
  u16* cde   = (u16*)take(300 * 2);
  u16* cW    = (u16*)take(90000 * 2);
  u16* cWih  = (u16*)take(360000 * 2);
  u16* cWhh  = (u16*)take(360000 * 2);
  u16* cbih  = (u16*)take(1200 * 2);
  u16* cbhh  = (u16*)take(1200 * 2);
  u16* crWih = (u16*)take(90000 * 2);
  u16* crWhh = (u16*)take(90000 * 2);
  u16* crbih = (u16*)take(300 * 2);
  u16* crbhh = (u16*)take(300 * 2);
  u32* flag  = (u32*)take(256);
  u16*   X     = (u16*)take((size_t)4096 * 320 * 2);
  u16*   Vb    = (u16*)take((size_t)4096 * 320 * 2);
  u16*   WihT  = (u16*)take((size_t)300 * 1200 * 2);
  u16*   pW5   = (u16*)take((size_t)409600 * 2);
  u16*   rWihT = (u16*)take((size_t)300 * 300 * 2);
  u16*   rWhhT = (u16*)take((size_t)300 * 300 * 2);
  // union: pAcc (8*4096*304*2 = 19.9MB, dead after k_combine) then xgp (21.0MB)
  char* uacc = take((size_t)20971520);
  u16*   pAcc = (u16*)uacc;
  float* xgp  = (float*)uacc;
  float* pML   = (float*)take((size_t)8 * 4096 * 2 * 4);
  float* H     = (float*)take((size_t)32 * 8 * 300 * 4);
  float* qbuf  = (float*)take((size_t)32 * 304 * 4);
  // union region: pA+pB (dead after k_softmax_v), then xg (row-major)
  char* ureg = take((size_t)25000192);
  u16*   pA = (u16*)ureg;
  u16*   pB = (u16*)(ureg + (size_t)625 * 10240 * 2);
  float* xg = (float*)ureg;

  k_ingest<<<4096, 256, 0, stream>>>(words, vocab, de, W, lWih, lWhh, lbih, lbhh,
                                     rWih, rWhh, rbih, rbhh,
                                     cw, cv, cde, cW, cWih, cWhh, cbih, cbhh,
                                     crWih, crWhh, crbih, crbhh, flag);
  k_transpose_bf<<<dim3(38, 10), 256, 0, stream>>>(cWih, WihT, 1200, 300);
  k_transpose_bf<<<dim3(10, 10), 256, 0, stream>>>(crWih, rWihT, 300, 300);
  k_transpose_bf<<<dim3(10, 10), 256, 0, stream>>>(crWhh, rWhhT, 300, 300);
  k_pack_w5<<<1600, 256, 0, stream>>>(cWhh, pW5);
  k_pack_vocab<<<625, 256, 0, stream>>>(cv, pA, pB);
  k_xw<<<dim3(3, 128), 256, 0, stream>>>(cw, cW, X);
  k_softmax_v<<<256, 512, 0, stream>>>(X, pA, pB, pAcc, pML);
  k_combine<<<4096, 320, 0, stream>>>(pAcc, pML, X, cde, cw, Vb);
  k_xg<<<dim3(10, 128), 256, 0, stream>>>(Vb, WihT, cbih, cbhh, xg);
  k_repack_xg<<<256, 256, 0, stream>>>(xg, xgp);
  k_lstm3<<<2, 1024, 0, stream>>>(xgp, pW5, lengths, qbuf);
  k_rnn<<<32, 320, 0, stream>>>(qbuf, rWihT, rWhhT, crbih, crbhh, H);
  k_attn<<<32, 256, 0, stream>>>(H, Vb, lengths, flag, d_out);
}

// Round 2
// 2685.750 us; speedup vs baseline: 1.1152x; 1.1152x over previous
//
#include <hip/hip_runtime.h>

// B=32, S=128, D=300 (pad 320), VOCAB=20000 (625 chunks of 32), K=8.
// Inputs may be f32 or bf16 (runtime-detected); canonicalized to bf16 in ws.

typedef unsigned short u16;
typedef unsigned int   u32;
typedef float  f32x4 __attribute__((ext_vector_type(4)));
typedef u32    u32x4 __attribute__((ext_vector_type(4)));
typedef __bf16 bf16x8 __attribute__((ext_vector_type(8)));
typedef _Float16 f16x8 __attribute__((ext_vector_type(8)));

#define SCOPE_AGENT __HIP_MEMORY_SCOPE_AGENT

__device__ __forceinline__ float bf2f(u16 u) { return __uint_as_float(((u32)u) << 16); }
__device__ __forceinline__ u16 f2bf(float f) {
  u32 x = __float_as_uint(f);
  u32 r = (x + 0x7fffu + ((x >> 16) & 1u)) >> 16;  // RNE
  return (u16)r;
}
__device__ __forceinline__ u16 f2h(float f) {
  union { _Float16 h; u16 u; } cv; cv.h = (_Float16)f; return cv.u;
}
__device__ __forceinline__ float h2f(u16 u) {
  union { _Float16 h; u16 u; } cv; cv.u = u; return (float)cv.h;
}
__device__ __forceinline__ float sigm_fast(float x) {
  return __builtin_amdgcn_rcpf(1.f + __expf(-x));
}
__device__ __forceinline__ float tanh_fast(float x) {
  return 1.f - 2.f * __builtin_amdgcn_rcpf(1.f + __expf(2.f * x));
}

// quad_perm DPP move (4-lane group permutation, VALU-only cross-lane)
template <int CTRL>
__device__ __forceinline__ float dppq(float v) {
  return __uint_as_float(
      (u32)__builtin_amdgcn_mov_dpp((int)__float_as_uint(v), CTRL, 0xF, 0xF, true));
}

__device__ __forceinline__ f32x4 shflx4(f32x4 v, int m) {
  f32x4 r;
  r[0] = __shfl_xor(v[0], m, 16);
  r[1] = __shfl_xor(v[1], m, 16);
  r[2] = __shfl_xor(v[2], m, 16);
  r[3] = __shfl_xor(v[3], m, 16);
  return r;
}

// ---------- ingest: detect f32 vs bf16, canonicalize all float inputs to bf16 ----------
__device__ __forceinline__ void conv_seg(const void* src, u16* dst, int n, int is32,
                                         int t0, int stride) {
  if (is32) {
    const float* s = (const float*)src;
    for (int i = t0; i < n; i += stride) dst[i] = f2bf(s[i]);
  } else {
    const u16* s = (const u16*)src;
    for (int i = t0; i < n; i += stride) dst[i] = s[i];
  }
}

__global__ __launch_bounds__(256) void k_ingest(
    const void* words, const void* vocab, const void* de, const void* W,
    const void* lWih, const void* lWhh, const void* lbih, const void* lbhh,
    const void* rWih, const void* rWhh, const void* rbih, const void* rbhh,
    u16* cw, u16* cv, u16* cde, u16* cW, u16* cWih, u16* cWhh, u16* cbih, u16* cbhh,
    u16* crWih, u16* crWhh, u16* crbih, u16* crbhh, u32* flag, u32* seqz, u32* hbz) {
  __shared__ int s_is32;
  int tid = threadIdx.x;
  int vote = 0;
  if (tid < 64) {
    u32 w = ((const u32*)words)[tid];
    int e = (w >> 7) & 0xFF;  // bf16 low-element exponent field if bf16-packed
    vote = (e >= 100 && e <= 150) ? 1 : 0;
  }
  unsigned long long m = __ballot(vote);
  if (tid == 0) s_is32 = (__popcll(m) < 32) ? 1 : 0;  // few plausible bf16 exps -> f32
  __syncthreads();
  int is32 = s_is32;
  if (blockIdx.x == 0 && tid == 0) *flag = (u32)is32;
  int t0 = blockIdx.x * 256 + tid;
  int stride = gridDim.x * 256;
  if (t0 < 256) seqz[t0] = 0;     // LSTM partner flags
  if (t0 < 10240) hbz[t0] = 0;    // LSTM h exchange buffers (2m x 2buf x 16 x 320 f16)
  conv_seg(words, cw, 1228800, is32, t0, stride);
  conv_seg(vocab, cv, 6000000, is32, t0, stride);
  conv_seg(de, cde, 300, is32, t0, stride);
  conv_seg(W, cW, 90000, is32, t0, stride);
  conv_seg(lWih, cWih, 360000, is32, t0, stride);
  conv_seg(lWhh, cWhh, 360000, is32, t0, stride);
  conv_seg(lbih, cbih, 1200, is32, t0, stride);
  conv_seg(lbhh, cbhh, 1200, is32, t0, stride);
  conv_seg(rWih, crWih, 90000, is32, t0, stride);
  conv_seg(rWhh, crWhh, 90000, is32, t0, stride);
  conv_seg(rbih, crbih, 300, is32, t0, stride);
  conv_seg(rbhh, crbhh, 300, is32, t0, stride);
}

// ---------- transpose bf16 (J x K) -> bf16 (K x J) ----------
__global__ __launch_bounds__(256) void k_transpose_bf(const u16* __restrict__ in,
                                                      u16* __restrict__ out,
                                                      int J, int K) {
  __shared__ u16 t[32][33];
  int j0 = blockIdx.x * 32, k0 = blockIdx.y * 32;
  int lx = threadIdx.x & 31, ly = threadIdx.x >> 5;
  for (int r = ly; r < 32; r += 8) {
    int j = j0 + r, k = k0 + lx;
    t[r][lx] = (j < J && k < K) ? in[(size_t)j * K + k] : (u16)0;
  }
  __syncthreads();
  for (int r = ly; r < 32; r += 8) {
    int k = k0 + r, j = j0 + lx;
    if (k < K && j < J) out[(size_t)k * J + j] = t[lx][r];
  }
}

// ---------- pack lstm_Whh -> per-(half,wave) MFMA B-frag slices (f16), gate-interleaved ----
// Block half nh owns dims [nh*160, nh*160+160) (valid <300). Wave w owns tiles
// jt = w*5+i (i=0..4); cols col = dd*4+g (dd local dim). Resident region (i<4):
// u16 idx = nh*204800 + ((w*4+i)*10+kt)*512 + lane*8 + jj. Spill region (i==4):
// u16 idx = nh*204800 + 163840 + (w*10+kt)*512 + lane*8 + jj.
// value: n16=lane&15, quad=lane>>4, g=n16&3, dd=jt*4+(n16>>2), dim=nh*160+dd,
//        k=kt*32+quad*8+jj; Whh[g*300+dim][k] (0 if dim>=300 or k>=300).
__global__ __launch_bounds__(256) void k_pack_w6(const u16* __restrict__ Whh,
                                                 u16* __restrict__ pW) {
  int idx = blockIdx.x * 256 + threadIdx.x;
  if (idx >= 409600) return;
  int nh = idx / 204800;
  int r = idx - nh * 204800;
  int jj = r & 7;
  int lane = (r >> 3) & 63;
  int rest = r >> 9;
  int kt, jt;
  if (r < 163840) {
    kt = rest % 10;
    int ti = rest / 10;      // 0..31 = w*4+i
    int w = ti >> 2, i = ti & 3;
    jt = w * 5 + i;
  } else {
    int rest2 = (r - 163840) >> 9;
    kt = rest2 % 10;
    int w = rest2 / 10;
    jt = w * 5 + 4;
  }
  int n16 = lane & 15, quad = lane >> 4;
  int g = n16 & 3;
  int dd = jt * 4 + (n16 >> 2);
  int dim = nh * 160 + dd;
  int k = kt * 32 + quad * 8 + jj;
  u16 out = 0;
  if (dim < 300 && k < 300)
    out = f2h(bf2f(Whh[(size_t)(g * 300 + dim) * 300 + k]));
  pW[idx] = out;
}

// ---------- pack vocab into MFMA operand layouts ----------
__global__ __launch_bounds__(256) void k_pack_vocab(const u16* __restrict__ vocab,
                                                    u16* __restrict__ pA,
                                                    u16* __restrict__ pB) {
  __shared__ u16 sv[32][320];
  int ci = blockIdx.x, tid = threadIdx.x;
  for (int idx = tid; idx < 32 * 20; idx += 256) {
    int v = idx / 20, k = 300 + (idx - v * 20);
    sv[v][k] = 0;
  }
  for (int idx = tid; idx < 32 * 300; idx += 256) {
    int v = idx / 300, k = idx - v * 300;
    sv[v][k] = vocab[(size_t)(ci * 32 + v) * 300 + k];
  }
  __syncthreads();
  for (int idx = tid; idx < 10240; idx += 256) {
    int j = idx & 7, lane = (idx >> 3) & 63, t2 = idx >> 9;
    int kk = t2 % 10, h = t2 / 10;
    int v = h * 16 + (lane & 15);
    int k = kk * 32 + ((lane >> 4)) * 8 + j;
    pA[(size_t)ci * 10240 + (size_t)idx] = sv[v][k];
  }
  for (int idx = tid; idx < 9728; idx += 256) {
    int j = idx & 7, lane = (idx >> 3) & 63, nc = idx >> 9;
    int v = (lane >> 4) * 8 + j;
    int n = nc * 16 + (lane & 15);
    pB[(size_t)ci * 9728 + (size_t)idx] = sv[v][n];
  }
}

// ---------- X = words @ W -> bf16 (4096 x 320, zero pad) ----------
__global__ __launch_bounds__(256) void k_xw(const u16* __restrict__ words,
                                            const u16* __restrict__ W,
                                            u16* __restrict__ X) {
  __shared__ float As[300][33];
  int n0 = blockIdx.x * 128;
  int r0 = blockIdx.y * 32;
  int tid = threadIdx.x;
  for (int idx = tid; idx < 32 * 300; idx += 256) {
    int r = idx / 300, k = idx - r * 300;
    As[k][r] = bf2f(words[(size_t)(r0 + r) * 300 + k]);
  }
  __syncthreads();
  int j = n0 + (tid & 127);
  int rh = (tid >> 7) * 16;
  float acc[16];
#pragma unroll
  for (int i = 0; i < 16; i++) acc[i] = 0.f;
  if (j < 300) {
    for (int k = 0; k < 300; k++) {
      float bw = bf2f(W[(size_t)k * 300 + j]);
#pragma unroll
      for (int i = 0; i < 16; i++) acc[i] += As[k][rh + i] * bw;
    }
  }
  if (j < 320) {
#pragma unroll
    for (int i = 0; i < 16; i++) {
      float v = (j < 300) ? acc[i] : 0.f;
      X[(size_t)(r0 + rh + i) * 320 + j] = f2bf(v);
    }
  }
}

// ---------- flash-style softmax-weighted vocab sum (MFMA), per-slice partials ----------
__global__ __launch_bounds__(512, 2) void k_softmax_v(
    const u16* __restrict__ X, const u16* __restrict__ pA, const u16* __restrict__ pB,
    u16* __restrict__ pAcc, float* __restrict__ pML) {
  __shared__ __align__(16) u16 chunk[19968];
  __shared__ __align__(16) float ptbuf[8 * 576];
  int bid = blockIdx.x;
  int sl = bid & 7, b = bid >> 3;
  int tid = threadIdx.x;
  int w = tid >> 6, lane = tid & 63;
  int quad = lane >> 4, n16 = lane & 15;
  int cs = (sl == 0) ? 0 : 79 + (sl - 1) * 78;
  int nch = (sl == 0) ? 79 : 78;

  int rowA = b * 128 + w * 16 + n16;
  const bf16x8* Xrow = (const bf16x8*)(X + (size_t)rowA * 320);
  bf16x8 afr[10];
#pragma unroll
  for (int kk = 0; kk < 10; kk++) afr[kk] = Xrow[kk * 4 + quad];

  f32x4 acc[19];
#pragma unroll
  for (int i = 0; i < 19; i++) { acc[i][0] = 0.f; acc[i][1] = 0.f; acc[i][2] = 0.f; acc[i][3] = 0.f; }
  f32x4 mrun, lrun;
#pragma unroll
  for (int c = 0; c < 4; c++) { mrun[c] = -1e30f; lrun[c] = 0.f; }
  float* myPt = ptbuf + w * 576;

  {
    const u32x4* gA = (const u32x4*)pA + (size_t)cs * 1280;
    const u32x4* gB = (const u32x4*)pB + (size_t)cs * 1216;
    u32x4* sb = (u32x4*)&chunk[0];
    for (int idx = tid; idx < 2496; idx += 512)
      sb[idx] = (idx < 1280) ? gA[idx] : gB[idx - 1280];
  }
  __syncthreads();

  for (int ic = 0; ic < nch; ic++) {
    u32x4 pf[5];
    bool havepf = (ic + 1 < nch);
    if (havepf) {
      int ci = cs + ic + 1;
      const u32x4* gA = (const u32x4*)pA + (size_t)ci * 1280;
      const u32x4* gB = (const u32x4*)pB + (size_t)ci * 1216;
#pragma unroll
      for (int i = 0; i < 5; i++) {
        int idx = tid + i * 512;
        if (idx < 2496) pf[i] = (idx < 1280) ? gA[idx] : gB[idx - 1280];
      }
    }
    const bf16x8* bufA = (const bf16x8*)&chunk[0];
    const bf16x8* bufB = (const bf16x8*)&chunk[10240];
    f32x4 L0, L1;
#pragma unroll
    for (int c = 0; c < 4; c++) { L0[c] = 0.f; L1[c] = 0.f; }
#pragma unroll
    for (int kk = 0; kk < 10; kk++) {
      L0 = __builtin_amdgcn_mfma_f32_16x16x32_bf16(afr[kk], bufA[kk * 64 + lane], L0, 0, 0, 0);
      L1 = __builtin_amdgcn_mfma_f32_16x16x32_bf16(afr[kk], bufA[(10 + kk) * 64 + lane], L1, 0, 0, 0);
    }
    f32x4 t;
#pragma unroll
    for (int c = 0; c < 4; c++) t[c] = fmaxf(L0[c], L1[c]);
#pragma unroll
    for (int off = 1; off < 16; off <<= 1) {
      f32x4 o = shflx4(t, off);
#pragma unroll
      for (int c = 0; c < 4; c++) t[c] = fmaxf(t[c], o[c]);
    }
    f32x4 mnew, al, P0v, P1v, rs;
#pragma unroll
    for (int c = 0; c < 4; c++) {
      mnew[c] = fmaxf(mrun[c], t[c]);
      al[c] = __expf(mrun[c] - mnew[c]);
      P0v[c] = __expf(L0[c] - mnew[c]);
      P1v[c] = __expf(L1[c] - mnew[c]);
      rs[c] = P0v[c] + P1v[c];
    }
#pragma unroll
    for (int off = 1; off < 16; off <<= 1) {
      f32x4 o = shflx4(rs, off);
#pragma unroll
      for (int c = 0; c < 4; c++) rs[c] += o[c];
    }
#pragma unroll
    for (int c = 0; c < 4; c++) { lrun[c] = lrun[c] * al[c] + rs[c]; mrun[c] = mnew[c]; }
#pragma unroll
    for (int r = 0; r < 4; r++) {
      myPt[(quad * 4 + r) * 36 + n16] = P0v[r];
      myPt[(quad * 4 + r) * 36 + 16 + n16] = P1v[r];
    }
    __syncthreads();
    f32x4 plo = *(const f32x4*)(myPt + n16 * 36 + quad * 8);
    f32x4 phi = *(const f32x4*)(myPt + n16 * 36 + quad * 8 + 4);
    bf16x8 paf;
#pragma unroll
    for (int c = 0; c < 4; c++) { paf[c] = (__bf16)plo[c]; paf[c + 4] = (__bf16)phi[c]; }
#pragma unroll
    for (int nc = 0; nc < 19; nc++) {
      f32x4 a = acc[nc];
#pragma unroll
      for (int c = 0; c < 4; c++) a[c] *= al[c];
      acc[nc] = __builtin_amdgcn_mfma_f32_16x16x32_bf16(paf, bufB[nc * 64 + lane], a, 0, 0, 0);
    }
    __syncthreads();
    if (havepf) {
      u32x4* sb = (u32x4*)&chunk[0];
#pragma unroll
      for (int i = 0; i < 5; i++) {
        int idx = tid + i * 512;
        if (idx < 2496) sb[idx] = pf[i];
      }
    }
    __syncthreads();
  }

  size_t prow = (size_t)sl * 4096 + (size_t)b * 128 + w * 16;
  if (n16 == 0) {
#pragma unroll
    for (int r = 0; r < 4; r++) {
      pML[(prow + quad * 4 + r) * 2 + 0] = mrun[r];
      pML[(prow + quad * 4 + r) * 2 + 1] = lrun[r];
    }
  }
#pragma unroll
  for (int nc = 0; nc < 19; nc++)
#pragma unroll
    for (int r = 0; r < 4; r++)
      pAcc[(prow + quad * 4 + r) * 304 + nc * 16 + n16] = f2bf(acc[nc][r]);
}

// ---------- combine slices + default-embed column -> V bf16 (4096 x 320) ----------
__global__ __launch_bounds__(320) void k_combine(
    const u16* __restrict__ pAcc, const float* __restrict__ pML,
    const u16* __restrict__ X, const u16* __restrict__ de,
    const u16* __restrict__ words, u16* __restrict__ Vout) {
  __shared__ float red[320];
  __shared__ float fs[8];
  __shared__ float sinv, sw;
  int row = blockIdx.x, tid = threadIdx.x;
  float p = 0.f;
  if (tid < 300) p = bf2f(X[(size_t)row * 320 + tid]) * bf2f(de[tid]);
  red[tid] = p;
  __syncthreads();
  if (tid == 0) {
    float d = 0.f;
    for (int i = 0; i < 300; i++) d += red[i];
    float mv[8], lv[8], ms = -1e30f;
    for (int s = 0; s < 8; s++) {
      mv[s] = pML[((size_t)s * 4096 + row) * 2];
      lv[s] = pML[((size_t)s * 4096 + row) * 2 + 1];
      ms = fmaxf(ms, mv[s]);
    }
    float mf = fmaxf(ms, d);
    float pd = __expf(d - mf);
    float l = pd;
    for (int s = 0; s < 8; s++) {
      float f = __expf(mv[s] - mf);
      fs[s] = f;
      l += lv[s] * f;
    }
    sinv = 1.f / l;
    sw = pd / l;
  }
  __syncthreads();
  float v = 0.f;
  if (tid < 300) {
    float a = 0.f;
#pragma unroll
    for (int s = 0; s < 8; s++)
      a += bf2f(pAcc[((size_t)s * 4096 + row) * 304 + tid]) * fs[s];
    v = a * sinv + sw * bf2f(words[(size_t)row * 300 + tid]);
  }
  Vout[(size_t)row * 320 + tid] = f2bf(v);
}

// ---------- xg = V @ lstm_Wih.T + bih + bhh (f32, 4096 x 1200, row-major) ----------
__global__ __launch_bounds__(256) void k_xg(const u16* __restrict__ Vb,
                                            const u16* __restrict__ WihT,
                                            const u16* __restrict__ bih,
                                            const u16* __restrict__ bhh,
                                            float* __restrict__ xg) {
  __shared__ float As[300][33];
  int n0 = blockIdx.x * 128;
  int r0 = blockIdx.y * 32;
  int tid = threadIdx.x;
  for (int idx = tid; idx < 32 * 300; idx += 256) {
    int r = idx / 300, k = idx - r * 300;
    As[k][r] = bf2f(Vb[(size_t)(r0 + r) * 320 + k]);
  }
  __syncthreads();
  int j = n0 + (tid & 127);
  if (j >= 1200) return;
  int rh = (tid >> 7) * 16;
  float acc[16];
#pragma unroll
  for (int i = 0; i < 16; i++) acc[i] = 0.f;
  for (int k = 0; k < 300; k++) {
    float bw = bf2f(WihT[(size_t)k * 1200 + j]);
#pragma unroll
    for (int i = 0; i < 16; i++) acc[i] += As[k][rh + i] * bw;
  }
  float bias = bf2f(bih[j]) + bf2f(bhh[j]);
#pragma unroll
  for (int i = 0; i < 16; i++)
    xg[(size_t)(r0 + rh + i) * 1200 + j] = acc[i] + bias;
}

// ---------- repack xg: [b*128+t][gate*300+dim] f32 -> xgp[((t*2+bm)*1280 + n)*16 + bl]
// n = dim*4+gate (gate-interleaved cols, batch-inner-16 for MFMA C-init loads)
__global__ __launch_bounds__(256) void k_repack_xg(const float* __restrict__ xg,
                                                   float* __restrict__ xgp) {
  __shared__ float s[16][81];
  int bid = blockIdx.x;
  int t = bid & 127, bm = bid >> 7;
  int tid = threadIdx.x;
  for (int w = 0; w < 16; w++) {
    for (int e = tid; e < 1280; e += 256) {
      int bl = e / 80, local = e - bl * 80;
      int g2 = local / 20, dd = local - g2 * 20;
      int dim = w * 20 + dd;
      float v = 0.f;
      if (dim < 300)
        v = xg[((size_t)(bm * 16 + bl) * 128 + t) * 1200 + g2 * 300 + dim];
      s[bl][dd * 4 + g2] = v;
    }
    __syncthreads();
    size_t ob = ((size_t)(t * 2 + bm) * 1280 + w * 80) * 16;
    for (int e = tid; e < 1280; e += 256) {
      int nl = e >> 4, bl = e & 15;
      xgp[ob + e] = s[bl][nl];
    }
    __syncthreads();
  }
}

// ---------- LSTM: 4 blocks = 2 M-groups x 2 dim-halves; pairwise coherent exchange ----
// Block (m,nh): 16 batches (1 Mtile), 160 dims (40 Ntiles of 16 gate-interleaved cols).
// 8 waves x 512 thr, cap 256 VGPR. Wave w: tiles jt=w*5+i; i<4 B-frags register-resident
// (160 VGPR), i==4 from LDS (80KB staged once). Per step: poll partner flag (relaxed,
// device-coherent) -> 40 relaxed-atomic dword A-loads (h_{t-1}, dbuf global) ->
// 50 MFMA (C-init = xg) -> DPP 4x4 transpose -> activations in regs -> h to LDS stage
// -> barrier -> coherent u32 publish -> barrier -> release flag. No 16-party all-to-all.
__global__ __launch_bounds__(512, 2) void k_lstm4(
    const float* __restrict__ xgp, const u16* __restrict__ pW,
    const int* __restrict__ lengths, u16* __restrict__ hbg,
    u32* __restrict__ seq, float* __restrict__ qbuf) {
  __shared__ __align__(16) u16 wsp[40960];   // 80KB: 8 spill B-tiles
  __shared__ u16 hst[16][168];               // h stage, this block's dim-half
  __shared__ int s_maxlen;
  int bid = blockIdx.x;
  int m = bid >> 1, nh = bid & 1;
  int tid = threadIdx.x;
  int w = tid >> 6, lane = tid & 63;
  int quad = lane >> 4, n16 = lane & 15;
  int g = n16 & 3, q4 = n16 >> 2;
  // stage spill weights -> LDS (contiguous copy)
  {
    const u32x4* src = (const u32x4*)(pW + (size_t)nh * 204800 + 163840);
    u32x4* dst = (u32x4*)wsp;
#pragma unroll
    for (int i = 0; i < 10; i++) dst[tid + i * 512] = src[tid + i * 512];
  }
  // zero h stage (pad dims must stay 0 -> zero weights see no NaN garbage)
  for (int i = tid; i < 16 * 168; i += 512) ((u16*)hst)[i] = 0;
  // maxlen over this m-group
  {
    int lv = (lane < 16) ? lengths[m * 16 + lane] : 0;
#pragma unroll
    for (int off = 1; off < 16; off <<= 1) {
      int o = __shfl_xor(lv, off, 64);
      lv = lv > o ? lv : o;
    }
    if (tid == 0) s_maxlen = lv;
  }
  // resident B-frags (tiles i=0..3)
  f16x8 bf[4][10];
  const u32x4* pw4 = (const u32x4*)(pW + (size_t)nh * 204800);
#pragma unroll
  for (int i = 0; i < 4; i++)
#pragma unroll
    for (int kt = 0; kt < 10; kt++)
      bf[i][kt] = __builtin_bit_cast(f16x8, pw4[((w * 4 + i) * 10 + kt) * 64 + lane]);
  int b = quad * 4 + g;  // batch (m-local) this lane owns post-transpose
  int len_b = lengths[m * 16 + b];
  float c[5];
#pragma unroll
  for (int i = 0; i < 5; i++) c[i] = 0.f;
  // xg C-init: xgp[((t*2+m)*1280 + nh*640 + (w*5+i)*16 + n16)*16 + quad*4 ..+3]
  const f32x4* xp0 = (const f32x4*)xgp +
                     ((size_t)m * 1280 + nh * 640 + w * 80 + n16) * 4 + quad;
  f32x4 xv[5];
#pragma unroll
  for (int i = 0; i < 5; i++) xv[i] = xp0[i * 64];
  u32* myf = seq + (size_t)bid * 64;
  const u32* paf = seq + (size_t)(bid ^ 1) * 64;
  const u32* hb32 = (const u32*)hbg;
  __syncthreads();
  int maxlen = s_maxlen;
  for (int t = 0; t < maxlen; t++) {
    if (t > 0) {
      while (__hip_atomic_load(paf, __ATOMIC_RELAXED, SCOPE_AGENT) < (u32)t)
        __builtin_amdgcn_s_sleep(1);
    }
    // A-frags: h_{t-1} for 16 batches, device-coherent dword loads (both halves)
    int rb = ((m * 2 + ((t + 1) & 1)) * 16 + n16) * 160 + quad * 4;
    u32x4 areg[10];
#pragma unroll
    for (int kt = 0; kt < 10; kt++)
#pragma unroll
      for (int d = 0; d < 4; d++)
        areg[kt][d] = __hip_atomic_load(hb32 + rb + kt * 16 + d,
                                        __ATOMIC_RELAXED, SCOPE_AGENT);
    bool upd = (t < len_b);
#pragma unroll
    for (int i = 0; i < 5; i++) {
      f32x4 acc = xv[i];
      if (t + 1 < maxlen) xv[i] = xp0[(size_t)(t + 1) * 10240 + i * 64];
#pragma unroll
      for (int kt = 0; kt < 10; kt++) {
        f16x8 a = __builtin_bit_cast(f16x8, areg[kt]);
        f16x8 bfr;
        if (i < 4) bfr = bf[i][kt];
        else bfr = __builtin_bit_cast(f16x8, ((const u32x4*)wsp)[(w * 10 + kt) * 64 + lane]);
        acc = __builtin_amdgcn_mfma_f32_16x16x32_f16(a, bfr, acc, 0, 0, 0);
      }
      // DPP 4x4 transpose: lane g gets all 4 gates of batch quad*4+g
      float v0 = acc[0], v1 = acc[1], v2 = acc[2], v3 = acc[3];
      float x0 = dppq<0xB1>(v0), x1 = dppq<0xB1>(v1);
      float x2 = dppq<0xB1>(v2), x3 = dppq<0xB1>(v3);
      bool o1 = (g & 1);
      float m0 = o1 ? x1 : v0;
      float m1 = o1 ? v1 : x0;
      float m2 = o1 ? x3 : v2;
      float m3 = o1 ? v3 : x2;
      float y0 = dppq<0x4E>(m0), y1 = dppq<0x4E>(m1);
      float y2 = dppq<0x4E>(m2), y3 = dppq<0x4E>(m3);
      bool o2 = (g & 2);
      float F0 = o2 ? y2 : m0;  // i
      float F1 = o2 ? y3 : m1;  // f
      float F2 = o2 ? m2 : y0;  // g
      float F3 = o2 ? m3 : y1;  // o
      float ii = sigm_fast(F0), ff = sigm_fast(F1);
      float gg = tanh_fast(F2), oo = sigm_fast(F3);
      float cn = ff * c[i] + ii * gg;
      float hn = oo * tanh_fast(cn);
      int dd = (w * 5 + i) * 4 + q4;
      if (upd) {
        c[i] = cn;
        if (nh * 160 + dd < 300) hst[b][dd] = f2h(hn);  // else hst keeps frozen h
      }
    }
    __syncthreads();
    // publish own half (16 x 160 f16 = 1280 u32), device-coherent
    {
      u32* dstp = (u32*)hbg + ((size_t)(m * 2 + (t & 1)) * 16) * 160 + (size_t)nh * 80;
      const u32* hsrc = (const u32*)&hst[0][0];
#pragma unroll
      for (int i = 0; i < 3; i++) {
        int e = tid + i * 512;
        if (e < 1280) {
          int bb = e / 80, kk = e - bb * 80;
          __hip_atomic_store(dstp + (size_t)bb * 160 + kk, hsrc[bb * 84 + kk],
                             __ATOMIC_RELAXED, SCOPE_AGENT);
        }
      }
    }
    __syncthreads();  // all publishes drained (vmcnt 0 before barrier)
    if (tid == 0)
      __hip_atomic_store(myf, (u32)(t + 1), __ATOMIC_RELEASE, SCOPE_AGENT);
  }
  // final q from hst (holds frozen h per batch)
  for (int e = tid; e < 2560; e += 512) {
    int bb = e / 160, kk = e - bb * 160;
    int dim = nh * 160 + kk;
    if (dim < 300) qbuf[(size_t)(m * 16 + bb) * 304 + dim] = h2f(hst[bb][kk]);
  }
}

// ---------- RNN tail: q from qbuf (f32), 8 steps h2 = tanh(base + h2@rWhh.T) ----------
__global__ __launch_bounds__(320) void k_rnn(
    const float* __restrict__ qbuf,
    const u16* __restrict__ rWihT, const u16* __restrict__ rWhhT,
    const u16* __restrict__ rbih, const u16* __restrict__ rbhh,
    float* __restrict__ H) {
  __shared__ float qs[304], h2[304], base[304];
  int b = blockIdx.x, tid = threadIdx.x;
  if (tid < 304) {
    qs[tid] = (tid < 300) ? qbuf[(size_t)b * 304 + tid] : 0.f;
    h2[tid] = 0.f;
  }
  __syncthreads();
  if (tid < 300) {
    float a = bf2f(rbih[tid]) + bf2f(rbhh[tid]);
    for (int k = 0; k < 300; k++) a += qs[k] * bf2f(rWihT[(size_t)k * 300 + tid]);
    base[tid] = a;
  }
  __syncthreads();
  for (int s = 0; s < 8; s++) {
    float nv = 0.f;
    if (tid < 300) {
      float a = base[tid];
      for (int k = 0; k < 300; k++) a += h2[k] * bf2f(rWhhT[(size_t)k * 300 + tid]);
      nv = tanhf(a);
    }
    __syncthreads();
    if (tid < 300) {
      h2[tid] = nv;
      H[((size_t)b * 8 + s) * 300 + tid] = nv;
    }
    __syncthreads();
  }
}

// ---------- attention readout ----------
__global__ __launch_bounds__(256) void k_attn(const float* __restrict__ H,
                                              const u16* __restrict__ Vb,
                                              const int* __restrict__ lengths,
                                              const u32* __restrict__ flag,
                                              void* __restrict__ dout) {
  __shared__ float Hs[8][304];
  __shared__ float sc[8][128];
  __shared__ float wsum[8];
  int b = blockIdx.x, tid = threadIdx.x;
  int len = lengths[b];
  int is32 = (int)*flag;
  for (int idx = tid; idx < 8 * 300; idx += 256) {
    int k = idx / 300, j = idx - k * 300;
    Hs[k][j] = H[((size_t)b * 8 + k) * 300 + j];
  }
  __syncthreads();
  for (int s = tid; s < len; s += 256) {
    const u16* vr = Vb + (size_t)(b * 128 + s) * 320;
    float a[8];
#pragma unroll
    for (int k = 0; k < 8; k++) a[k] = 0.f;
    for (int j = 0; j < 300; j++) {
      float v = bf2f(vr[j]);
#pragma unroll
      for (int k = 0; k < 8; k++) a[k] += Hs[k][j] * v;
    }
#pragma unroll
    for (int k = 0; k < 8; k++) sc[k][s] = a[k];
  }
  __syncthreads();
  if (tid < 8) {
    float m = -1e30f;
    for (int s = 0; s < len; s++) m = fmaxf(m, sc[tid][s]);
    float l = 0.f;
    for (int s = 0; s < len; s++) { float e = __expf(sc[tid][s] - m); sc[tid][s] = e; l += e; }
    wsum[tid] = 1.f / l;
  }
  __syncthreads();
  int k = tid >> 5, jl = tid & 31;
  for (int j = jl; j < 300; j += 32) {
    float a = 0.f;
    for (int s = 0; s < len; s++) a += sc[k][s] * bf2f(Vb[(size_t)(b * 128 + s) * 320 + j]);
    float val = a * wsum[k];
    size_t o = ((size_t)b * 8 + k) * 300 + j;
    if (is32) ((float*)dout)[o] = val;
    else ((u16*)dout)[o] = f2bf(val);
  }
}

extern "C" void kernel_launch(void* const* d_in, const int* in_sizes, int n_in,
                              void* d_out, int out_size, void* d_ws, size_t ws_size,
                              hipStream_t stream) {
  (void)in_sizes; (void)n_in; (void)out_size; (void)ws_size;
  const void* words = d_in[0];
  const int* lengths = (const int*)d_in[1];
  const void* vocab = d_in[2];
  const void* de = d_in[3];
  const void* W = d_in[4];
  const void* lWih = d_in[5];
  const void* lWhh = d_in[6];
  const void* lbih = d_in[7];
  const void* lbhh = d_in[8];
  const void* rWih = d_in[9];
  const void* rWhh = d_in[10];
  const void* rbih = d_in[11];
  const void* rbhh = d_in[12];

  char* basep = (char*)d_ws;
  size_t off = 0;
  auto take = [&](size_t bytes) -> char* {
    char* p = basep + off;
    off += (bytes + 255) & ~(size_t)255;
    return p;
  };
  u16* cw    = (u16*)take(1228800 * 2);
  u16* cv    = (u16*)take(6000000 * 2);
  u16* cde   = (u16*)take(300 * 2);
  u16* cW    = (u16*)take(90000 * 2);
  u16* cWih  = (u16*)take(360000 * 2);
  u16* cWhh  = (u16*)take(360000 * 2);
  u16* cbih  = (u16*)take(1200 * 2);
  u16* cbhh  = (u16*)take(1200 * 2);
  u16* crWih = (u16*)take(90000 * 2);
  u16* crWhh = (u16*)take(90000 * 2);
  u16* crbih = (u16*)take(300 * 2);
  u16* crbhh = (u16*)take(300 * 2);
  u32* flag  = (u32*)take(256);
  u16*   X     = (u16*)take((size_t)4096 * 320 * 2);
  u16*   Vb    = (u16*)take((size_t)4096 * 320 * 2);
  u16*   WihT  = (u16*)take((size_t)300 * 1200 * 2);
  u16*   pW6   = (u16*)take((size_t)409600 * 2);
  u16*   rWihT = (u16*)take((size_t)300 * 300 * 2);
  u16*   rWhhT = (u16*)take((size_t)300 * 300 * 2);
  // union: pAcc (8*4096*304*2 = 19.9MB, dead after k_combine) then xgp (21.0MB)
  char* uacc = take((size_t)20971520);
  u16*   pAcc = (u16*)uacc;
  float* xgp  = (float*)uacc;
  float* pML   = (float*)take((size_t)8 * 4096 * 2 * 4);
  float* H     = (float*)take((size_t)32 * 8 * 300 * 4);
  float* qbuf  = (float*)take((size_t)32 * 304 * 4);
  u16*   hbg   = (u16*)take((size_t)2 * 2 * 16 * 320 * 2);  // [m][buf][16][320]
  u32*   seq   = (u32*)take((size_t)1024);
  // union region: pA+pB (dead after k_softmax_v), then xg (row-major)
  char* ureg = take((size_t)25000192);
  u16*   pA = (u16*)ureg;
  u16*   pB = (u16*)(ureg + (size_t)625 * 10240 * 2);
  float* xg = (float*)ureg;

  k_ingest<<<4096, 256, 0, stream>>>(words, vocab, de, W, lWih, lWhh, lbih, lbhh,
                                     rWih, rWhh, rbih, rbhh,
                                     cw, cv, cde, cW, cWih, cWhh, cbih, cbhh,
                                     crWih, crWhh, crbih, crbhh, flag, seq, (u32*)hbg);
  k_transpose_bf<<<dim3(38, 10), 256, 0, stream>>>(cWih, WihT, 1200, 300);
  k_transpose_bf<<<dim3(10, 10), 256, 0, stream>>>(crWih, rWihT, 300, 300);
  k_transpose_bf<<<dim3(10, 10), 256, 0, stream>>>(crWhh, rWhhT, 300, 300);
  k_pack_w6<<<1600, 256, 0, stream>>>(cWhh, pW6);
  k_pack_vocab<<<625, 256, 0, stream>>>(cv, pA, pB);
  k_xw<<<dim3(3, 128), 256, 0, stream>>>(cw, cW, X);
  k_softmax_v<<<256, 512, 0, stream>>>(X, pA, pB, pAcc, pML);
  k_combine<<<4096, 320, 0, stream>>>(pAcc, pML, X, cde, cw, Vb);
  k_xg<<<dim3(10, 128), 256, 0, stream>>>(Vb, WihT, cbih, cbhh, xg);
  k_repack_xg<<<256, 256, 0, stream>>>(xg, xgp);
  k_lstm4<<<4, 512, 0, stream>>>(xgp, pW6, lengths, hbg, seq, qbuf);
  k_rnn<<<32, 320, 0, stream>>>(qbuf, rWihT, rWhhT, crbih, crbhh, H);
  k_attn<<<32, 256, 0, stream>>>(H, Vb, lengths, flag, d_out);
}

// Round 5
// 1127.305 us; speedup vs baseline: 2.6570x; 2.3825x over previous
//
#include <hip/hip_runtime.h>

// B=32, S=128, D=300 (pad 320), VOCAB=20000 (625 chunks of 32), K=8.
// Inputs may be f32 or bf16 (runtime-detected); canonicalized to bf16 in ws.

typedef unsigned short u16;
typedef unsigned int   u32;
typedef float  f32x4 __attribute__((ext_vector_type(4)));
typedef u32    u32x4 __attribute__((ext_vector_type(4)));
typedef __bf16 bf16x8 __attribute__((ext_vector_type(8)));
typedef _Float16 f16x8 __attribute__((ext_vector_type(8)));

#define SCOPE_AGENT __HIP_MEMORY_SCOPE_AGENT

__device__ __forceinline__ float bf2f(u16 u) { return __uint_as_float(((u32)u) << 16); }
__device__ __forceinline__ u16 f2bf(float f) {
  u32 x = __float_as_uint(f);
  u32 r = (x + 0x7fffu + ((x >> 16) & 1u)) >> 16;  // RNE
  return (u16)r;
}
__device__ __forceinline__ u16 f2h(float f) {
  union { _Float16 h; u16 u; } cv; cv.h = (_Float16)f; return cv.u;
}
__device__ __forceinline__ float h2f(u16 u) {
  union { _Float16 h; u16 u; } cv; cv.u = u; return (float)cv.h;
}
__device__ __forceinline__ float sigm_fast(float x) {
  return __builtin_amdgcn_rcpf(1.f + __expf(-x));
}
__device__ __forceinline__ float tanh_fast(float x) {
  return 1.f - 2.f * __builtin_amdgcn_rcpf(1.f + __expf(2.f * x));
}

__device__ __forceinline__ f32x4 shflx4(f32x4 v, int m) {
  f32x4 r;
  r[0] = __shfl_xor(v[0], m, 16);
  r[1] = __shfl_xor(v[1], m, 16);
  r[2] = __shfl_xor(v[2], m, 16);
  r[3] = __shfl_xor(v[3], m, 16);
  return r;
}

// ---------- ingest: detect f32 vs bf16, canonicalize all float inputs to bf16 ----------
__device__ __forceinline__ void conv_seg(const void* src, u16* dst, int n, int is32,
                                         int t0, int stride) {
  if (is32) {
    const float* s = (const float*)src;
    for (int i = t0; i < n; i += stride) dst[i] = f2bf(s[i]);
  } else {
    const u16* s = (const u16*)src;
    for (int i = t0; i < n; i += stride) dst[i] = s[i];
  }
}

__global__ __launch_bounds__(256) void k_ingest(
    const void* words, const void* vocab, const void* de, const void* W,
    const void* lWih, const void* lWhh, const void* lbih, const void* lbhh,
    const void* rWih, const void* rWhh, const void* rbih, const void* rbhh,
    u16* cw, u16* cv, u16* cde, u16* cW, u16* cWih, u16* cWhh, u16* cbih, u16* cbhh,
    u16* crWih, u16* crWhh, u16* crbih, u16* crbhh, u32* flag, u32* seqz, u32* hbz) {
  __shared__ int s_is32;
  int tid = threadIdx.x;
  int vote = 0;
  if (tid < 64) {
    u32 w = ((const u32*)words)[tid];
    int e = (w >> 7) & 0xFF;  // bf16 low-element exponent field if bf16-packed
    vote = (e >= 100 && e <= 150) ? 1 : 0;
  }
  unsigned long long m = __ballot(vote);
  if (tid == 0) s_is32 = (__popcll(m) < 32) ? 1 : 0;  // few plausible bf16 exps -> f32
  __syncthreads();
  int is32 = s_is32;
  if (blockIdx.x == 0 && tid == 0) *flag = (u32)is32;
  int t0 = blockIdx.x * 256 + tid;
  int stride = gridDim.x * 256;
  if (t0 < 256) seqz[t0] = 0;     // LSTM producer flags
  if (t0 < 10240) hbz[t0] = 0;    // LSTM h exchange (2 bufs x 4 planes x 1280 u32)
  conv_seg(words, cw, 1228800, is32, t0, stride);
  conv_seg(vocab, cv, 6000000, is32, t0, stride);
  conv_seg(de, cde, 300, is32, t0, stride);
  conv_seg(W, cW, 90000, is32, t0, stride);
  conv_seg(lWih, cWih, 360000, is32, t0, stride);
  conv_seg(lWhh, cWhh, 360000, is32, t0, stride);
  conv_seg(lbih, cbih, 1200, is32, t0, stride);
  conv_seg(lbhh, cbhh, 1200, is32, t0, stride);
  conv_seg(rWih, crWih, 90000, is32, t0, stride);
  conv_seg(rWhh, crWhh, 90000, is32, t0, stride);
  conv_seg(rbih, crbih, 300, is32, t0, stride);
  conv_seg(rbhh, crbhh, 300, is32, t0, stride);
}

// ---------- transpose bf16 (J x K) -> bf16 (K x J) ----------
__global__ __launch_bounds__(256) void k_transpose_bf(const u16* __restrict__ in,
                                                      u16* __restrict__ out,
                                                      int J, int K) {
  __shared__ u16 t[32][33];
  int j0 = blockIdx.x * 32, k0 = blockIdx.y * 32;
  int lx = threadIdx.x & 31, ly = threadIdx.x >> 5;
  for (int r = ly; r < 32; r += 8) {
    int j = j0 + r, k = k0 + lx;
    t[r][lx] = (j < J && k < K) ? in[(size_t)j * K + k] : (u16)0;
  }
  __syncthreads();
  for (int r = ly; r < 32; r += 8) {
    int k = k0 + r, j = j0 + lx;
    if (k < K && j < J) out[(size_t)k * J + j] = t[lx][r];
  }
}

// ---------- pack lstm_Whh -> per-block MFMA B-frag slices (f16), LDS-streamed ----------
// Block bid owns dims [38*bid, 38*bid+nd) (nd=38, last 34); cols n = gate*40+dl (160).
// Layout: pW[bid*51200 + ((w*10+kt)*64 + lane)*8 + j] f16; wave-tile w = n>>4.
// n = w*16 + (lane&15); gate = n/40; dl = n%40; dim = 38*bid+dl;
// k = kt*32 + (lane>>4)*8 + j; val = Whh[gate*300+dim][k] (0 if dl>=nd or k>=300).
__global__ __launch_bounds__(256) void k_pack_w8(const u16* __restrict__ Whh,
                                                 u16* __restrict__ pW) {
  int idx = blockIdx.x * 256 + threadIdx.x;
  if (idx >= 409600) return;
  int bid = idx / 51200;
  int r = idx - bid * 51200;
  int j = r & 7;
  int lane = (r >> 3) & 63;
  int t2 = r >> 9;           // 0..99 = w*10 + kt
  int kt = t2 % 10, w = t2 / 10;
  int n16 = lane & 15, quad = lane >> 4;
  int n = w * 16 + n16;
  int gate = n / 40, dl = n - gate * 40;
  int nd = (bid < 7) ? 38 : 34;
  int dim = 38 * bid + dl;
  int k = kt * 32 + quad * 8 + j;
  u16 out = 0;
  if (dl < nd && k < 300)
    out = f2h(bf2f(Whh[(size_t)(gate * 300 + dim) * 300 + k]));
  pW[idx] = out;
}

// ---------- pack vocab into MFMA operand layouts ----------
__global__ __launch_bounds__(256) void k_pack_vocab(const u16* __restrict__ vocab,
                                                    u16* __restrict__ pA,
                                                    u16* __restrict__ pB) {
  __shared__ u16 sv[32][320];
  int ci = blockIdx.x, tid = threadIdx.x;
  for (int idx = tid; idx < 32 * 20; idx += 256) {
    int v = idx / 20, k = 300 + (idx - v * 20);
    sv[v][k] = 0;
  }
  for (int idx = tid; idx < 32 * 300; idx += 256) {
    int v = idx / 300, k = idx - v * 300;
    sv[v][k] = vocab[(size_t)(ci * 32 + v) * 300 + k];
  }
  __syncthreads();
  for (int idx = tid; idx < 10240; idx += 256) {
    int j = idx & 7, lane = (idx >> 3) & 63, t2 = idx >> 9;
    int kk = t2 % 10, h = t2 / 10;
    int v = h * 16 + (lane & 15);
    int k = kk * 32 + ((lane >> 4)) * 8 + j;
    pA[(size_t)ci * 10240 + (size_t)idx] = sv[v][k];
  }
  for (int idx = tid; idx < 9728; idx += 256) {
    int j = idx & 7, lane = (idx >> 3) & 63, nc = idx >> 9;
    int v = (lane >> 4) * 8 + j;
    int n = nc * 16 + (lane & 15);
    pB[(size_t)ci * 9728 + (size_t)idx] = sv[v][n];
  }
}

// ---------- X = words @ W -> bf16 (4096 x 320, zero pad) ----------
__global__ __launch_bounds__(256) void k_xw(const u16* __restrict__ words,
                                            const u16* __restrict__ W,
                                            u16* __restrict__ X) {
  __shared__ float As[300][33];
  int n0 = blockIdx.x * 128;
  int r0 = blockIdx.y * 32;
  int tid = threadIdx.x;
  for (int idx = tid; idx < 32 * 300; idx += 256) {
    int r = idx / 300, k = idx - r * 300;
    As[k][r] = bf2f(words[(size_t)(r0 + r) * 300 + k]);
  }
  __syncthreads();
  int j = n0 + (tid & 127);
  int rh = (tid >> 7) * 16;
  float acc[16];
#pragma unroll
  for (int i = 0; i < 16; i++) acc[i] = 0.f;
  if (j < 300) {
    for (int k = 0; k < 300; k++) {
      float bw = bf2f(W[(size_t)k * 300 + j]);
#pragma unroll
      for (int i = 0; i < 16; i++) acc[i] += As[k][rh + i] * bw;
    }
  }
  if (j < 320) {
#pragma unroll
    for (int i = 0; i < 16; i++) {
      float v = (j < 300) ? acc[i] : 0.f;
      X[(size_t)(r0 + rh + i) * 320 + j] = f2bf(v);
    }
  }
}

// ---------- flash-style softmax-weighted vocab sum (MFMA), per-slice partials ----------
__global__ __launch_bounds__(512, 2) void k_softmax_v(
    const u16* __restrict__ X, const u16* __restrict__ pA, const u16* __restrict__ pB,
    u16* __restrict__ pAcc, float* __restrict__ pML) {
  __shared__ __align__(16) u16 chunk[19968];
  __shared__ __align__(16) float ptbuf[8 * 576];
  int bid = blockIdx.x;
  int sl = bid & 7, b = bid >> 3;
  int tid = threadIdx.x;
  int w = tid >> 6, lane = tid & 63;
  int quad = lane >> 4, n16 = lane & 15;
  int cs = (sl == 0) ? 0 : 79 + (sl - 1) * 78;
  int nch = (sl == 0) ? 79 : 78;

  int rowA = b * 128 + w * 16 + n16;
  const bf16x8* Xrow = (const bf16x8*)(X + (size_t)rowA * 320);
  bf16x8 afr[10];
#pragma unroll
  for (int kk = 0; kk < 10; kk++) afr[kk] = Xrow[kk * 4 + quad];

  f32x4 acc[19];
#pragma unroll
  for (int i = 0; i < 19; i++) { acc[i][0] = 0.f; acc[i][1] = 0.f; acc[i][2] = 0.f; acc[i][3] = 0.f; }
  f32x4 mrun, lrun;
#pragma unroll
  for (int c = 0; c < 4; c++) { mrun[c] = -1e30f; lrun[c] = 0.f; }
  float* myPt = ptbuf + w * 576;

  {
    const u32x4* gA = (const u32x4*)pA + (size_t)cs * 1280;
    const u32x4* gB = (const u32x4*)pB + (size_t)cs * 1216;
    u32x4* sb = (u32x4*)&chunk[0];
    for (int idx = tid; idx < 2496; idx += 512)
      sb[idx] = (idx < 1280) ? gA[idx] : gB[idx - 1280];
  }
  __syncthreads();

  for (int ic = 0; ic < nch; ic++) {
    u32x4 pf[5];
    bool havepf = (ic + 1 < nch);
    if (havepf) {
      int ci = cs + ic + 1;
      const u32x4* gA = (const u32x4*)pA + (size_t)ci * 1280;
      const u32x4* gB = (const u32x4*)pB + (size_t)ci * 1216;
#pragma unroll
      for (int i = 0; i < 5; i++) {
        int idx = tid + i * 512;
        if (idx < 2496) pf[i] = (idx < 1280) ? gA[idx] : gB[idx - 1280];
      }
    }
    const bf16x8* bufA = (const bf16x8*)&chunk[0];
    const bf16x8* bufB = (const bf16x8*)&chunk[10240];
    f32x4 L0, L1;
#pragma unroll
    for (int c = 0; c < 4; c++) { L0[c] = 0.f; L1[c] = 0.f; }
#pragma unroll
    for (int kk = 0; kk < 10; kk++) {
      L0 = __builtin_amdgcn_mfma_f32_16x16x32_bf16(afr[kk], bufA[kk * 64 + lane], L0, 0, 0, 0);
      L1 = __builtin_amdgcn_mfma_f32_16x16x32_bf16(afr[kk], bufA[(10 + kk) * 64 + lane], L1, 0, 0, 0);
    }
    f32x4 t;
#pragma unroll
    for (int c = 0; c < 4; c++) t[c] = fmaxf(L0[c], L1[c]);
#pragma unroll
    for (int off = 1; off < 16; off <<= 1) {
      f32x4 o = shflx4(t, off);
#pragma unroll
      for (int c = 0; c < 4; c++) t[c] = fmaxf(t[c], o[c]);
    }
    f32x4 mnew, al, P0v, P1v, rs;
#pragma unroll
    for (int c = 0; c < 4; c++) {
      mnew[c] = fmaxf(mrun[c], t[c]);
      al[c] = __expf(mrun[c] - mnew[c]);
      P0v[c] = __expf(L0[c] - mnew[c]);
      P1v[c] = __expf(L1[c] - mnew[c]);
      rs[c] = P0v[c] + P1v[c];
    }
#pragma unroll
    for (int off = 1; off < 16; off <<= 1) {
      f32x4 o = shflx4(rs, off);
#pragma unroll
      for (int c = 0; c < 4; c++) rs[c] += o[c];
    }
#pragma unroll
    for (int c = 0; c < 4; c++) { lrun[c] = lrun[c] * al[c] + rs[c]; mrun[c] = mnew[c]; }
#pragma unroll
    for (int r = 0; r < 4; r++) {
      myPt[(quad * 4 + r) * 36 + n16] = P0v[r];
      myPt[(quad * 4 + r) * 36 + 16 + n16] = P1v[r];
    }
    __syncthreads();
    f32x4 plo = *(const f32x4*)(myPt + n16 * 36 + quad * 8);
    f32x4 phi = *(const f32x4*)(myPt + n16 * 36 + quad * 8 + 4);
    bf16x8 paf;
#pragma unroll
    for (int c = 0; c < 4; c++) { paf[c] = (__bf16)plo[c]; paf[c + 4] = (__bf16)phi[c]; }
#pragma unroll
    for (int nc = 0; nc < 19; nc++) {
      f32x4 a = acc[nc];
#pragma unroll
      for (int c = 0; c < 4; c++) a[c] *= al[c];
      acc[nc] = __builtin_amdgcn_mfma_f32_16x16x32_bf16(paf, bufB[nc * 64 + lane], a, 0, 0, 0);
    }
    __syncthreads();
    if (havepf) {
      u32x4* sb = (u32x4*)&chunk[0];
#pragma unroll
      for (int i = 0; i < 5; i++) {
        int idx = tid + i * 512;
        if (idx < 2496) sb[idx] = pf[i];
      }
    }
    __syncthreads();
  }

  size_t prow = (size_t)sl * 4096 + (size_t)b * 128 + w * 16;
  if (n16 == 0) {
#pragma unroll
    for (int r = 0; r < 4; r++) {
      pML[(prow + quad * 4 + r) * 2 + 0] = mrun[r];
      pML[(prow + quad * 4 + r) * 2 + 1] = lrun[r];
    }
  }
#pragma unroll
  for (int nc = 0; nc < 19; nc++)
#pragma unroll
    for (int r = 0; r < 4; r++)
      pAcc[(prow + quad * 4 + r) * 304 + nc * 16 + n16] = f2bf(acc[nc][r]);
}

// ---------- combine slices + default-embed column -> V bf16 (4096 x 320) ----------
__global__ __launch_bounds__(320) void k_combine(
    const u16* __restrict__ pAcc, const float* __restrict__ pML,
    const u16* __restrict__ X, const u16* __restrict__ de,
    const u16* __restrict__ words, u16* __restrict__ Vout) {
  __shared__ float red[320];
  __shared__ float fs[8];
  __shared__ float sinv, sw;
  int row = blockIdx.x, tid = threadIdx.x;
  float p = 0.f;
  if (tid < 300) p = bf2f(X[(size_t)row * 320 + tid]) * bf2f(de[tid]);
  red[tid] = p;
  __syncthreads();
  if (tid == 0) {
    float d = 0.f;
    for (int i = 0; i < 300; i++) d += red[i];
    float mv[8], lv[8], ms = -1e30f;
    for (int s = 0; s < 8; s++) {
      mv[s] = pML[((size_t)s * 4096 + row) * 2];
      lv[s] = pML[((size_t)s * 4096 + row) * 2 + 1];
      ms = fmaxf(ms, mv[s]);
    }
    float mf = fmaxf(ms, d);
    float pd = __expf(d - mf);
    float l = pd;
    for (int s = 0; s < 8; s++) {
      float f = __expf(mv[s] - mf);
      fs[s] = f;
      l += lv[s] * f;
    }
    sinv = 1.f / l;
    sw = pd / l;
  }
  __syncthreads();
  float v = 0.f;
  if (tid < 300) {
    float a = 0.f;
#pragma unroll
    for (int s = 0; s < 8; s++)
      a += bf2f(pAcc[((size_t)s * 4096 + row) * 304 + tid]) * fs[s];
    v = a * sinv + sw * bf2f(words[(size_t)row * 300 + tid]);
  }
  Vout[(size_t)row * 320 + tid] = f2bf(v);
}

// ---------- xg = V @ lstm_Wih.T + bih + bhh (f32, 4096 x 1200, row-major) ----------
__global__ __launch_bounds__(256) void k_xg(const u16* __restrict__ Vb,
                                            const u16* __restrict__ WihT,
                                            const u16* __restrict__ bih,
                                            const u16* __restrict__ bhh,
                                            float* __restrict__ xg) {
  __shared__ float As[300][33];
  int n0 = blockIdx.x * 128;
  int r0 = blockIdx.y * 32;
  int tid = threadIdx.x;
  for (int idx = tid; idx < 32 * 300; idx += 256) {
    int r = idx / 300, k = idx - r * 300;
    As[k][r] = bf2f(Vb[(size_t)(r0 + r) * 320 + k]);
  }
  __syncthreads();
  int j = n0 + (tid & 127);
  if (j >= 1200) return;
  int rh = (tid >> 7) * 16;
  float acc[16];
#pragma unroll
  for (int i = 0; i < 16; i++) acc[i] = 0.f;
  for (int k = 0; k < 300; k++) {
    float bw = bf2f(WihT[(size_t)k * 1200 + j]);
#pragma unroll
    for (int i = 0; i < 16; i++) acc[i] += As[k][rh + i] * bw;
  }
  float bias = bf2f(bih[j]) + bf2f(bhh[j]);
#pragma unroll
  for (int i = 0; i < 16; i++)
    xg[(size_t)(r0 + rh + i) * 1200 + j] = acc[i] + bias;
}

// ---------- LSTM: 8 blocks, LDS weights, plane-coalesced coherent h exchange ----------
// Block bid owns dims [38*bid, +nd) x 4 gates (N=160 cols, gate*40+dl). 10 waves;
// wave w = N-tile w. Weights streamed from LDS (100 KB) -> no VGPR spill.
// h exchange: global, 2 bufs x 4 dword-planes x 1280 chunks u32. Relaxed agent
// atomics (LLC-coherent, no L2 invalidate) + per-block release flag. Per step:
// poll 8 flags -> 80 coalesced relaxed dword A-loads -> 20 MFMA/wave (B from LDS)
// -> gl LDS -> activations (c,h in regs) -> 2 u16 relaxed stores -> barrier -> flag.
// u16 store index: plane p=(dim>>1)&3 (stride 1280 u32 = 2560 u16), chunk ch,
// halfword dim&1 -> so = (p*1280 + ch)*2 + (dim&1).
__global__ __launch_bounds__(640, 1) void k_lstm5(
    const float* __restrict__ xg, const u16* __restrict__ pW,
    const int* __restrict__ lengths, u32* __restrict__ hb,
    u32* __restrict__ seq, float* __restrict__ qbuf) {
  __shared__ __align__(16) u16 wlds[51200];  // 100 KB B-frags
  __shared__ float gl[32][164];              // stride 164: quad offsets {0,16}, 2-way free
  __shared__ int s_maxlen;
  int bid = blockIdx.x, tid = threadIdx.x;
  int w = tid >> 6, lane = tid & 63;
  int quad = lane >> 4, n16 = lane & 15;
  int nd = (bid < 7) ? 38 : 34;
  // stage weights -> LDS (contiguous)
  {
    const u32x4* src = (const u32x4*)(pW + (size_t)bid * 51200);
    u32x4* dst = (u32x4*)wlds;
#pragma unroll
    for (int i = 0; i < 10; i++) dst[tid + i * 640] = src[tid + i * 640];
  }
  // maxlen over all 32 batches
  {
    int lv = (tid < 32) ? lengths[tid] : 0;
#pragma unroll
    for (int off = 1; off < 32; off <<= 1) {
      int o = __shfl_xor(lv, off, 64);
      lv = lv > o ? lv : o;
    }
    if (tid == 0) s_maxlen = lv;
  }
  // activation ownership: thread owns (b0=tid/40, dl=tid%40) and (b0+16, dl)
  int b0 = tid / 40, dl = tid - b0 * 40;
  int b1 = b0 + 16;
  bool act = dl < nd;
  int dim = 38 * bid + dl;
  int len0 = lengths[b0], len1 = lengths[b1];
  // h store offsets (u16 index within one buffer of 10240 u16)
  int p = (dim >> 1) & 3;
  int chq = ((dim >> 3) & 3) * 16;
  int ch0 = ((0 * 10 + (dim >> 5)) * 64 + chq + (b0 & 15));
  int ch1 = ((1 * 10 + (dim >> 5)) * 64 + chq + (b1 & 15));
  int so0 = (p * 1280 + ch0) * 2 + (dim & 1);
  int so1 = (p * 1280 + ch1) * 2 + (dim & 1);
  u16* hb16 = (u16*)hb;
  float c0 = 0.f, h0 = 0.f, c1 = 0.f, h1 = 0.f;
  u32* myf = seq + (size_t)bid * 16;
  __syncthreads();
  int maxlen = s_maxlen;
  for (int t = 0; t < maxlen; t++) {
    if (tid < 8) {
      while (__hip_atomic_load(&seq[tid * 16], __ATOMIC_RELAXED, SCOPE_AGENT) < (u32)t)
        __builtin_amdgcn_s_sleep(1);
    }
    __syncthreads();
    // xv loads (plain; xg stays L2-warm since we never invalidate)
    float xv00 = 0.f, xv01 = 0.f, xv02 = 0.f, xv03 = 0.f;
    float xv10 = 0.f, xv11 = 0.f, xv12 = 0.f, xv13 = 0.f;
    if (act) {
      const float* xr0 = xg + ((size_t)b0 * 128 + t) * 1200 + dim;
      const float* xr1 = xg + ((size_t)b1 * 128 + t) * 1200 + dim;
      xv00 = xr0[0]; xv01 = xr0[300]; xv02 = xr0[600]; xv03 = xr0[900];
      xv10 = xr1[0]; xv11 = xr1[300]; xv12 = xr1[600]; xv13 = xr1[900];
    }
    // A-frags: h_t for 32 batches; plane layout -> lane-consecutive dword loads
    const u32* hbt = hb + (size_t)(t & 1) * 5120;
    u32x4 af[2][10];
#pragma unroll
    for (int mt = 0; mt < 2; mt++)
#pragma unroll
      for (int kt = 0; kt < 10; kt++)
#pragma unroll
        for (int pp = 0; pp < 4; pp++)
          af[mt][kt][pp] = __hip_atomic_load(
              hbt + pp * 1280 + (mt * 10 + kt) * 64 + lane,
              __ATOMIC_RELAXED, SCOPE_AGENT);
    // MFMA: B from LDS, reused across both M-tiles
    const u32x4* wl = (const u32x4*)wlds;
    f32x4 C0, C1;
    C0[0] = 0.f; C0[1] = 0.f; C0[2] = 0.f; C0[3] = 0.f;
    C1[0] = 0.f; C1[1] = 0.f; C1[2] = 0.f; C1[3] = 0.f;
#pragma unroll
    for (int kt = 0; kt < 10; kt++) {
      f16x8 bfr = __builtin_bit_cast(f16x8, wl[(w * 10 + kt) * 64 + lane]);
      C0 = __builtin_amdgcn_mfma_f32_16x16x32_f16(
          __builtin_bit_cast(f16x8, af[0][kt]), bfr, C0, 0, 0, 0);
      C1 = __builtin_amdgcn_mfma_f32_16x16x32_f16(
          __builtin_bit_cast(f16x8, af[1][kt]), bfr, C1, 0, 0, 0);
    }
#pragma unroll
    for (int rr = 0; rr < 4; rr++) {
      gl[quad * 4 + rr][w * 16 + n16] = C0[rr];
      gl[16 + quad * 4 + rr][w * 16 + n16] = C1[rr];
    }
    __syncthreads();
    int bufo = ((t + 1) & 1) * 10240;
    if (act) {
      {
        float gi = gl[b0][dl] + xv00, gf = gl[b0][40 + dl] + xv01;
        float gg = gl[b0][80 + dl] + xv02, go = gl[b0][120 + dl] + xv03;
        if (t < len0) {
          c0 = sigm_fast(gf) * c0 + sigm_fast(gi) * tanh_fast(gg);
          h0 = sigm_fast(go) * tanh_fast(c0);
        }
        __hip_atomic_store(hb16 + bufo + so0, f2h(h0), __ATOMIC_RELAXED, SCOPE_AGENT);
      }
      {
        float gi = gl[b1][dl] + xv10, gf = gl[b1][40 + dl] + xv11;
        float gg = gl[b1][80 + dl] + xv12, go = gl[b1][120 + dl] + xv13;
        if (t < len1) {
          c1 = sigm_fast(gf) * c1 + sigm_fast(gi) * tanh_fast(gg);
          h1 = sigm_fast(go) * tanh_fast(c1);
        }
        __hip_atomic_store(hb16 + bufo + so1, f2h(h1), __ATOMIC_RELAXED, SCOPE_AGENT);
      }
    }
    __syncthreads();  // drains vmem stores block-wide before release
    if (tid == 0)
      __hip_atomic_store(myf, (u32)(t + 1), __ATOMIC_RELEASE, SCOPE_AGENT);
  }
  // final q (h frozen at len per batch)
  if (act) {
    qbuf[(size_t)b0 * 304 + dim] = h0;
    qbuf[(size_t)b1 * 304 + dim] = h1;
  }
}

// ---------- RNN tail: q from qbuf (f32), 8 steps h2 = tanh(base + h2@rWhh.T) ----------
__global__ __launch_bounds__(320) void k_rnn(
    const float* __restrict__ qbuf,
    const u16* __restrict__ rWihT, const u16* __restrict__ rWhhT,
    const u16* __restrict__ rbih, const u16* __restrict__ rbhh,
    float* __restrict__ H) {
  __shared__ float qs[304], h2[304], base[304];
  int b = blockIdx.x, tid = threadIdx.x;
  if (tid < 304) {
    qs[tid] = (tid < 300) ? qbuf[(size_t)b * 304 + tid] : 0.f;
    h2[tid] = 0.f;
  }
  __syncthreads();
  if (tid < 300) {
    float a = bf2f(rbih[tid]) + bf2f(rbhh[tid]);
    for (int k = 0; k < 300; k++) a += qs[k] * bf2f(rWihT[(size_t)k * 300 + tid]);
    base[tid] = a;
  }
  __syncthreads();
  for (int s = 0; s < 8; s++) {
    float nv = 0.f;
    if (tid < 300) {
      float a = base[tid];
      for (int k = 0; k < 300; k++) a += h2[k] * bf2f(rWhhT[(size_t)k * 300 + tid]);
      nv = tanhf(a);
    }
    __syncthreads();
    if (tid < 300) {
      h2[tid] = nv;
      H[((size_t)b * 8 + s) * 300 + tid] = nv;
    }
    __syncthreads();
  }
}

// ---------- attention readout ----------
__global__ __launch_bounds__(256) void k_attn(const float* __restrict__ H,
                                              const u16* __restrict__ Vb,
                                              const int* __restrict__ lengths,
                                              const u32* __restrict__ flag,
                                              void* __restrict__ dout) {
  __shared__ float Hs[8][304];
  __shared__ float sc[8][128];
  __shared__ float wsum[8];
  int b = blockIdx.x, tid = threadIdx.x;
  int len = lengths[b];
  int is32 = (int)*flag;
  for (int idx = tid; idx < 8 * 300; idx += 256) {
    int k = idx / 300, j = idx - k * 300;
    Hs[k][j] = H[((size_t)b * 8 + k) * 300 + j];
  }
  __syncthreads();
  for (int s = tid; s < len; s += 256) {
    const u16* vr = Vb + (size_t)(b * 128 + s) * 320;
    float a[8];
#pragma unroll
    for (int k = 0; k < 8; k++) a[k] = 0.f;
    for (int j = 0; j < 300; j++) {
      float v = bf2f(vr[j]);
#pragma unroll
      for (int k = 0; k < 8; k++) a[k] += Hs[k][j] * v;
    }
#pragma unroll
    for (int k = 0; k < 8; k++) sc[k][s] = a[k];
  }
  __syncthreads();
  if (tid < 8) {
    float m = -1e30f;
    for (int s = 0; s < len; s++) m = fmaxf(m, sc[tid][s]);
    float l = 0.f;
    for (int s = 0; s < len; s++) { float e = __expf(sc[tid][s] - m); sc[tid][s] = e; l += e; }
    wsum[tid] = 1.f / l;
  }
  __syncthreads();
  int k = tid >> 5, jl = tid & 31;
  for (int j = jl; j < 300; j += 32) {
    float a = 0.f;
    for (int s = 0; s < len; s++) a += sc[k][s] * bf2f(Vb[(size_t)(b * 128 + s) * 320 + j]);
    float val = a * wsum[k];
    size_t o = ((size_t)b * 8 + k) * 300 + j;
    if (is32) ((float*)dout)[o] = val;
    else ((u16*)dout)[o] = f2bf(val);
  }
}

extern "C" void kernel_launch(void* const* d_in, const int* in_sizes, int n_in,
                              void* d_out, int out_size, void* d_ws, size_t ws_size,
                              hipStream_t stream) {
  (void)in_sizes; (void)n_in; (void)out_size; (void)ws_size;
  const void* words = d_in[0];
  const int* lengths = (const int*)d_in[1];
  const void* vocab = d_in[2];
  const void* de = d_in[3];
  const void* W = d_in[4];
  const void* lWih = d_in[5];
  const void* lWhh = d_in[6];
  const void* lbih = d_in[7];
  const void* lbhh = d_in[8];
  const void* rWih = d_in[9];
  const void* rWhh = d_in[10];
  const void* rbih = d_in[11];
  const void* rbhh = d_in[12];

  char* basep = (char*)d_ws;
  size_t off = 0;
  auto take = [&](size_t bytes) -> char* {
    char* p = basep + off;
    off += (bytes + 255) & ~(size_t)255;
    return p;
  };
  u16* cw    = (u16*)take(1228800 * 2);
  u16* cv    = (u16*)take(6000000 * 2);
  u16* cde   = (u16*)take(300 * 2);
  u16* cW    = (u16*)take(90000 * 2);
  u16* cWih  = (u16*)take(360000 * 2);
  u16* cWhh  = (u16*)take(360000 * 2);
  u16* cbih  = (u16*)take(1200 * 2);
  u16* cbhh  = (u16*)take(1200 * 2);
  u16* crWih = (u16*)take(90000 * 2);
  u16* crWhh = (u16*)take(90000 * 2);
  u16* crbih = (u16*)take(300 * 2);
  u16* crbhh = (u16*)take(300 * 2);
  u32* flag  = (u32*)take(256);
  u16*   X     = (u16*)take((size_t)4096 * 320 * 2);
  u16*   Vb    = (u16*)take((size_t)4096 * 320 * 2);
  u16*   WihT  = (u16*)take((size_t)300 * 1200 * 2);
  u16*   pW8   = (u16*)take((size_t)409600 * 2);
  u16*   rWihT = (u16*)take((size_t)300 * 300 * 2);
  u16*   rWhhT = (u16*)take((size_t)300 * 300 * 2);
  u16*   pAcc  = (u16*)take((size_t)8 * 4096 * 304 * 2);
  float* pML   = (float*)take((size_t)8 * 4096 * 2 * 4);
  float* H     = (float*)take((size_t)32 * 8 * 300 * 4);
  float* qbuf  = (float*)take((size_t)32 * 304 * 4);
  u32*   hbg   = (u32*)take((size_t)10240 * 4);  // 2 bufs x 4 planes x 1280 u32
  u32*   seq   = (u32*)take((size_t)1024);
  // union region: pA+pB (dead after k_softmax_v), then xg (row-major)
  char* ureg = take((size_t)25000192);
  u16*   pA = (u16*)ureg;
  u16*   pB = (u16*)(ureg + (size_t)625 * 10240 * 2);
  float* xg = (float*)ureg;

  k_ingest<<<4096, 256, 0, stream>>>(words, vocab, de, W, lWih, lWhh, lbih, lbhh,
                                     rWih, rWhh, rbih, rbhh,
                                     cw, cv, cde, cW, cWih, cWhh, cbih, cbhh,
                                     crWih, crWhh, crbih, crbhh, flag, seq, hbg);
  k_transpose_bf<<<dim3(38, 10), 256, 0, stream>>>(cWih, WihT, 1200, 300);
  k_transpose_bf<<<dim3(10, 10), 256, 0, stream>>>(crWih, rWihT, 300, 300);
  k_transpose_bf<<<dim3(10, 10), 256, 0, stream>>>(crWhh, rWhhT, 300, 300);
  k_pack_w8<<<1600, 256, 0, stream>>>(cWhh, pW8);
  k_pack_vocab<<<625, 256, 0, stream>>>(cv, pA, pB);
  k_xw<<<dim3(3, 128), 256, 0, stream>>>(cw, cW, X);
  k_softmax_v<<<256, 512, 0, stream>>>(X, pA, pB, pAcc, pML);
  k_combine<<<4096, 320, 0, stream>>>(pAcc, pML, X, cde, cw, Vb);
  k_xg<<<dim3(10, 128), 256, 0, stream>>>(Vb, WihT, cbih, cbhh, xg);
  k_lstm5<<<8, 640, 0, stream>>>(xg, pW8, lengths, hbg, seq, qbuf);
  k_rnn<<<32, 320, 0, stream>>>(qbuf, rWihT, rWhhT, crbih, crbhh, H);
  k_attn<<<32, 256, 0, stream>>>(H, Vb, lengths, flag, d_out);
}